// Round 11
// baseline (181.636 us; speedup 1.0000x reference)
//
#include <hip/hip_runtime.h>

#define BB 32768
#define BS (BB*16)   // 524288

typedef float v2f __attribute__((ext_vector_type(2)));

// forced packed-f32 FMA (compiler was scalarizing v2f ops — r10 busy-time evidence)
__device__ __forceinline__ v2f pk_fma(v2f a, v2f b, v2f c){
    v2f d;
    asm("v_pk_fma_f32 %0, %1, %2, %3" : "=v"(d) : "v"(a), "v"(b), "v"(c));
    return d;
}
__device__ __forceinline__ v2f pk_fma_lo(v2f a, v2f b, v2f c){  // both halves use a.lo
    v2f d;
    asm("v_pk_fma_f32 %0, %1, %2, %3 op_sel:[0,0,0] op_sel_hi:[0,1,1]"
        : "=v"(d) : "v"(a), "v"(b), "v"(c));
    return d;
}
__device__ __forceinline__ v2f pk_fma_hi(v2f a, v2f b, v2f c){  // both halves use a.hi
    v2f d;
    asm("v_pk_fma_f32 %0, %1, %2, %3 op_sel:[1,0,0] op_sel_hi:[1,1,1]"
        : "=v"(d) : "v"(a), "v"(b), "v"(c));
    return d;
}

// ---- ws float offsets ----
#define RECO 64
#define TAB  128             // disc F table, 2049 floats over [-8,8], step 1/128
#define NTAB 2049
#define HFO  8448
#define HBO  (HFO+BS)

// ---- table-kernel LDS layout ----
#define PW0 0
#define PB0 96
#define PW1 192
#define PB1 1920
#define PW2 1968
#define PB2 2448
#define PW3 2472
#define PB3 3048
#define PW4 3096
#define PB4 5016
#define POW 5112
#define POB 5144
#define PN  5148

__device__ __forceinline__ float sigm(float x){
    return __builtin_amdgcn_rcpf(1.f + __expf(-x));
}
__device__ __forceinline__ float tanh_f(float x){
    return 1.f - 2.f * __builtin_amdgcn_rcpf(1.f + __expf(2.f * x));
}
__device__ __forceinline__ float dunit(float gi, float gg, float go){
    return sigm(go) * tanh_f(sigm(gi) * tanh_f(gg));
}

struct P29 { const float* p[29]; };
// 0 values 1 masks 2-4 g_fwd(Wih,Whh,b) 5-7 g_bwd 8 impW 9 impb
// 10 fcW 11 fcb 12-14 dec(Wih,Whh,b) 15 dec_out_W 16 dec_out_b 17 disc_out_W
// 18 disc_out_b 19/20 d_W_0/d_b_0 ... 27/28 d_W_4/d_b_4

// ==== k_lstm: 16 lanes per (b,dir), 16 groups/block, small private LDS
//      (4.2KB — r7/r9/r10 evidence: measured occupancy tracks LDS size). ====
__global__ __launch_bounds__(256)
void k_lstm(P29 a, const int* __restrict__ masks, float* __restrict__ ws)
{
    __shared__ __align__(16) float smem[1040];   // h: 16 sets x 48; x: 16 x 17
    int tid = threadIdx.x;
    int lane = tid & 63;
    int gbase = lane & 48;
    int u = tid & 15;
    int setw = tid >> 4;
    int gid = blockIdx.x * 16 + setw;            // 0..65535
    int dir = gid >> 15;
    int b = gid & 32767;
    const float* __restrict__ Whh = a.p[3 + 3*dir];
    v2f wif[16], wgo[16];
    #pragma unroll
    for (int q = 0; q < 4; q++) {
        float4 vi = ((const float4*)(Whh + (u)*16))[q];
        float4 vf = ((const float4*)(Whh + (16+u)*16))[q];
        float4 vg = ((const float4*)(Whh + (32+u)*16))[q];
        float4 vo = ((const float4*)(Whh + (48+u)*16))[q];
        wif[4*q+0] = (v2f){vi.x, vf.x}; wgo[4*q+0] = (v2f){vg.x, vo.x};
        wif[4*q+1] = (v2f){vi.y, vf.y}; wgo[4*q+1] = (v2f){vg.y, vo.y};
        wif[4*q+2] = (v2f){vi.z, vf.z}; wgo[4*q+2] = (v2f){vg.z, vo.z};
        wif[4*q+3] = (v2f){vi.w, vf.w}; wgo[4*q+3] = (v2f){vg.w, vo.w};
    }
    const float* __restrict__ Wih = a.p[2 + 3*dir];
    const float* __restrict__ bia = a.p[4 + 3*dir];
    v2f xif = (v2f){Wih[u], Wih[16+u]}, xgo = (v2f){Wih[32+u], Wih[48+u]};
    v2f bif = (v2f){bia[u], bia[16+u]}, bgo = (v2f){bia[32+u], bia[48+u]};
    v2f impw2[8];
    #pragma unroll
    for (int q = 0; q < 4; q++) {
        float4 v = ((const float4*)a.p[8])[q];
        impw2[2*q+0] = (v2f){v.x, v.y};
        impw2[2*q+1] = (v2f){v.z, v.w};
    }
    float impb = a.p[9][0];
    float x_own = a.p[0][(size_t)b*16 + u];
    int   m_own = masks[(size_t)b*16 + u];
    unsigned mm = (unsigned)(__ballot(m_own != 0) >> gbase) & 0xffffu;
    int xo = 768 + setw*17;
    smem[xo + u] = x_own;
    // initial state: x=+/-128, h=c=0 (f-gate dead)
    float sgn = dir ? -128.f : 128.f;
    float giI = sgn*xif.x + bif.x, ggI = sgn*xgo.x + bgo.x, goI = sgn*xgo.y + bgo.y;
    float c = sigm(giI) * tanh_f(ggI);
    float h = sigm(goI) * tanh_f(c);
    int wa = setw*48 + u;                        // even/odd sets alternate bank halves
    int ra = setw*12;                            // float4 index of h row
    const float4* lhv = (const float4*)smem;
    #pragma unroll
    for (int t = 0; t < 16; t++) {
        smem[wa] = h;                            // DS in-order per wave
        float4 h0 = lhv[ra + 0];
        float4 h1 = lhv[ra + 1];
        float4 h2 = lhv[ra + 2];
        float4 h3 = lhv[ra + 3];
        v2f p0 = (v2f){h0.x, h0.y}, p1 = (v2f){h0.z, h0.w};
        v2f p2 = (v2f){h1.x, h1.y}, p3 = (v2f){h1.z, h1.w};
        v2f p4 = (v2f){h2.x, h2.y}, p5 = (v2f){h2.z, h2.w};
        v2f p6 = (v2f){h3.x, h3.y}, p7 = (v2f){h3.z, h3.w};
        // imp dot (pairwise packed, horizontal at end)
        v2f ia = (v2f){impb, 0.f};
        ia = pk_fma(p0, impw2[0], ia); ia = pk_fma(p1, impw2[1], ia);
        ia = pk_fma(p2, impw2[2], ia); ia = pk_fma(p3, impw2[3], ia);
        ia = pk_fma(p4, impw2[4], ia); ia = pk_fma(p5, impw2[5], ia);
        ia = pk_fma(p6, impw2[6], ia); ia = pk_fma(p7, impw2[7], ia);
        float imp = ia.x + ia.y;
        float xt = smem[xo + t];
        float cc = ((mm >> t) & 1u) ? imp : xt;
        v2f ccv = (v2f){cc, cc};
        v2f gif = pk_fma(ccv, xif, bif);
        v2f ggo = pk_fma(ccv, xgo, bgo);
        // 32 packed FMAs, h broadcast via op_sel (no splat movs)
        gif = pk_fma_lo(p0, wif[0],  gif); ggo = pk_fma_lo(p0, wgo[0],  ggo);
        gif = pk_fma_hi(p0, wif[1],  gif); ggo = pk_fma_hi(p0, wgo[1],  ggo);
        gif = pk_fma_lo(p1, wif[2],  gif); ggo = pk_fma_lo(p1, wgo[2],  ggo);
        gif = pk_fma_hi(p1, wif[3],  gif); ggo = pk_fma_hi(p1, wgo[3],  ggo);
        gif = pk_fma_lo(p2, wif[4],  gif); ggo = pk_fma_lo(p2, wgo[4],  ggo);
        gif = pk_fma_hi(p2, wif[5],  gif); ggo = pk_fma_hi(p2, wgo[5],  ggo);
        gif = pk_fma_lo(p3, wif[6],  gif); ggo = pk_fma_lo(p3, wgo[6],  ggo);
        gif = pk_fma_hi(p3, wif[7],  gif); ggo = pk_fma_hi(p3, wgo[7],  ggo);
        gif = pk_fma_lo(p4, wif[8],  gif); ggo = pk_fma_lo(p4, wgo[8],  ggo);
        gif = pk_fma_hi(p4, wif[9],  gif); ggo = pk_fma_hi(p4, wgo[9],  ggo);
        gif = pk_fma_lo(p5, wif[10], gif); ggo = pk_fma_lo(p5, wgo[10], ggo);
        gif = pk_fma_hi(p5, wif[11], gif); ggo = pk_fma_hi(p5, wgo[11], ggo);
        gif = pk_fma_lo(p6, wif[12], gif); ggo = pk_fma_lo(p6, wgo[12], ggo);
        gif = pk_fma_hi(p6, wif[13], gif); ggo = pk_fma_hi(p6, wgo[13], ggo);
        gif = pk_fma_lo(p7, wif[14], gif); ggo = pk_fma_lo(p7, wgo[14], ggo);
        gif = pk_fma_hi(p7, wif[15], gif); ggo = pk_fma_hi(p7, wgo[15], ggo);
        float cn = sigm(gif.y)*c + sigm(gif.x)*tanh_f(ggo.x);
        c = cn;
        h = sigm(ggo.y)*tanh_f(cn);
    }
    ws[HFO + (size_t)dir*BS + (size_t)b*16 + u] = h;
}

// ==== k_tabdec: blocks 0..128 = disc F table (16 lanes/entry, LDS-staged);
//      block 129 = batch-invariant decoder scan ====
__global__ __launch_bounds__(256)
void k_tabdec(P29 a, float* __restrict__ ws)
{
    __shared__ __align__(16) float wl[PN];
    int tid = threadIdx.x;
    if (blockIdx.x < 129) {
#define STAGE(WS, BSi, h, K, padK, wdst, bdst) \
    { const float* Wp = a.p[WS]; const float* Bp = a.p[BSi]; \
      for (int i = tid; i < 3*(h)*(K); i += 256){ \
        int r = i/(K), k = i - r*(K); int g = r/(h), u0 = r - g*(h); \
        int sr = (g==0? u0 : (g==1? 2*(h)+u0 : 3*(h)+u0)); \
        wl[(wdst) + r*(padK) + k] = Wp[sr*(K) + k]; } \
      for (int i = tid; i < 3*(h); i += 256){ \
        int g = i/(h), u0 = i - g*(h); \
        int sr = (g==0? u0 : (g==1? 2*(h)+u0 : 3*(h)+u0)); \
        wl[(bdst) + i] = Bp[sr]; } }
        STAGE(19, 20, 32,  1,  1, PW0, PB0)
        STAGE(21, 22, 16, 32, 36, PW1, PB1)
        STAGE(23, 24,  8, 16, 20, PW2, PB2)
        STAGE(25, 26, 16,  8, 12, PW3, PB3)
        STAGE(27, 28, 32, 16, 20, PW4, PB4)
#undef STAGE
        { const float* s = a.p[17]; for (int i = tid; i < 32; i += 256) wl[POW+i] = s[i]; }
        if (tid == 0) wl[POB] = a.p[18][0];
        __syncthreads();
        int u = tid & 15;
        int gbase = (tid & 63) & 48;
        int gid = blockIdx.x * 16 + (tid >> 4);
        const float4* w4 = (const float4*)wl;
        float xin = -8.f + (float)gid * (1.f/128.f);
        float lo = dunit(xin*wl[PW0+u]    + wl[PB0+u],
                         xin*wl[PW0+32+u] + wl[PB0+32+u],
                         xin*wl[PW0+64+u] + wl[PB0+64+u]);
        float hi = dunit(xin*wl[PW0+16+u] + wl[PB0+16+u],
                         xin*wl[PW0+48+u] + wl[PB0+48+u],
                         xin*wl[PW0+80+u] + wl[PB0+80+u]);
        float A0[32];
        #pragma unroll
        for (int k = 0; k < 16; k++) { A0[k] = __shfl(lo, gbase+k); A0[16+k] = __shfl(hi, gbase+k); }
        float gi = wl[PB1+u], gg = wl[PB1+16+u], go = wl[PB1+32+u];
        int bi_ = (PW1 + u*36)>>2, bg_ = (PW1 + (16+u)*36)>>2, bo_ = (PW1 + (32+u)*36)>>2;
        #pragma unroll
        for (int q = 0; q < 8; q++) {
            float4 wi = w4[bi_+q], wg = w4[bg_+q], wo = w4[bo_+q];
            float b0=A0[4*q], b1=A0[4*q+1], b2=A0[4*q+2], b3=A0[4*q+3];
            gi += b0*wi.x + b1*wi.y + b2*wi.z + b3*wi.w;
            gg += b0*wg.x + b1*wg.y + b2*wg.z + b3*wg.w;
            go += b0*wo.x + b1*wo.y + b2*wo.z + b3*wo.w;
        }
        float a1 = dunit(gi, gg, go);
        float A1[16];
        #pragma unroll
        for (int k = 0; k < 16; k++) A1[k] = __shfl(a1, gbase+k);
        int v = u & 7;
        gi = wl[PB2+v]; gg = wl[PB2+8+v]; go = wl[PB2+16+v];
        bi_ = (PW2 + v*20)>>2; bg_ = (PW2 + (8+v)*20)>>2; bo_ = (PW2 + (16+v)*20)>>2;
        #pragma unroll
        for (int q = 0; q < 4; q++) {
            float4 wi = w4[bi_+q], wg = w4[bg_+q], wo = w4[bo_+q];
            float b0=A1[4*q], b1=A1[4*q+1], b2=A1[4*q+2], b3=A1[4*q+3];
            gi += b0*wi.x + b1*wi.y + b2*wi.z + b3*wi.w;
            gg += b0*wg.x + b1*wg.y + b2*wg.z + b3*wg.w;
            go += b0*wo.x + b1*wo.y + b2*wo.z + b3*wo.w;
        }
        float a2 = dunit(gi, gg, go);
        float A2[8];
        #pragma unroll
        for (int k = 0; k < 8; k++) A2[k] = __shfl(a2, gbase+k);
        gi = wl[PB3+u]; gg = wl[PB3+16+u]; go = wl[PB3+32+u];
        bi_ = (PW3 + u*12)>>2; bg_ = (PW3 + (16+u)*12)>>2; bo_ = (PW3 + (32+u)*12)>>2;
        #pragma unroll
        for (int q = 0; q < 2; q++) {
            float4 wi = w4[bi_+q], wg = w4[bg_+q], wo = w4[bo_+q];
            float b0=A2[4*q], b1=A2[4*q+1], b2=A2[4*q+2], b3=A2[4*q+3];
            gi += b0*wi.x + b1*wi.y + b2*wi.z + b3*wi.w;
            gg += b0*wg.x + b1*wg.y + b2*wg.z + b3*wg.w;
            go += b0*wo.x + b1*wo.y + b2*wo.z + b3*wo.w;
        }
        float a3 = dunit(gi, gg, go);
        float A3[16];
        #pragma unroll
        for (int k = 0; k < 16; k++) A3[k] = __shfl(a3, gbase+k);
        float part;
        {
            float g0i = wl[PB4+u], g0g = wl[PB4+32+u], g0o = wl[PB4+64+u];
            float g1i = wl[PB4+16+u], g1g = wl[PB4+48+u], g1o = wl[PB4+80+u];
            int c0i = (PW4 + u*20)>>2,      c0g = (PW4 + (32+u)*20)>>2, c0o = (PW4 + (64+u)*20)>>2;
            int c1i = (PW4 + (16+u)*20)>>2, c1g = (PW4 + (48+u)*20)>>2, c1o = (PW4 + (80+u)*20)>>2;
            #pragma unroll
            for (int q = 0; q < 4; q++) {
                float b0=A3[4*q], b1=A3[4*q+1], b2=A3[4*q+2], b3=A3[4*q+3];
                float4 wi = w4[c0i+q], wg = w4[c0g+q], wo = w4[c0o+q];
                g0i += b0*wi.x + b1*wi.y + b2*wi.z + b3*wi.w;
                g0g += b0*wg.x + b1*wg.y + b2*wg.z + b3*wg.w;
                g0o += b0*wo.x + b1*wo.y + b2*wo.z + b3*wo.w;
                wi = w4[c1i+q]; wg = w4[c1g+q]; wo = w4[c1o+q];
                g1i += b0*wi.x + b1*wi.y + b2*wi.z + b3*wi.w;
                g1g += b0*wg.x + b1*wg.y + b2*wg.z + b3*wg.w;
                g1o += b0*wo.x + b1*wo.y + b2*wo.z + b3*wo.w;
            }
            part = dunit(g0i, g0g, g0o)*wl[POW+u] + dunit(g1i, g1g, g1o)*wl[POW+16+u];
        }
        part += __shfl_xor(part, 1);
        part += __shfl_xor(part, 2);
        part += __shfl_xor(part, 4);
        part += __shfl_xor(part, 8);
        if (u == 0 && gid < NTAB) ws[TAB + gid] = part + wl[POB];
        return;
    }
    // ---------------- decoder block ----------------
    {
        float* dh = wl;
        float* dc = wl + 16;
        const float* Wih = a.p[12];
        const float* Whh = a.p[13];
        const float* bb  = a.p[14];
        const float* oW  = a.p[15];
        const float* ob  = a.p[16];
        float wii[16], wff[16], wgg[16], woo[16];
        float vii[16], vff[16], vgg[16], voo[16];
        float bi_r=0, bf_r=0, bg_r=0, bo_r=0;
        if (tid < 16) {
            int uu = tid;
            #pragma unroll
            for (int k = 0; k < 16; k++) {
                wii[k]=Wih[uu*16+k];      vii[k]=Whh[uu*16+k];
                wff[k]=Wih[(16+uu)*16+k]; vff[k]=Whh[(16+uu)*16+k];
                wgg[k]=Wih[(32+uu)*16+k]; vgg[k]=Whh[(32+uu)*16+k];
                woo[k]=Wih[(48+uu)*16+k]; voo[k]=Whh[(48+uu)*16+k];
            }
            bi_r=bb[uu]; bf_r=bb[16+uu]; bg_r=bb[32+uu]; bo_r=bb[48+uu];
            float gi = bi_r, gg = bg_r, go = bo_r;
            #pragma unroll
            for (int k = 0; k < 16; k++) {
                gi += 128.f * wii[k];
                gg += 128.f * wgg[k];
                go += 128.f * woo[k];
            }
            float c0 = sigm(gi) * tanh_f(gg);
            dc[tid] = c0; dh[tid] = sigm(go) * tanh_f(c0);
        }
        __syncthreads();
        for (int t = 0; t < 16; t++) {
            float rx[16], rh[16], cold = 0.f;
            if (tid < 16) {
                #pragma unroll
                for (int k = 0; k < 16; k++) { rx[k] = dc[k]; rh[k] = dh[k]; }
                cold = dc[tid];
            }
            __syncthreads();
            if (tid < 16) {
                float gi = bi_r, gf = bf_r, gg = bg_r, go = bo_r;
                #pragma unroll
                for (int k = 0; k < 16; k++) {
                    gi += rx[k]*wii[k] + rh[k]*vii[k];
                    gf += rx[k]*wff[k] + rh[k]*vff[k];
                    gg += rx[k]*wgg[k] + rh[k]*vgg[k];
                    go += rx[k]*woo[k] + rh[k]*voo[k];
                }
                float cn = sigm(gf)*cold + sigm(gi)*tanh_f(gg);
                dc[tid] = cn; dh[tid] = sigm(go)*tanh_f(cn);
            }
            __syncthreads();
            if (tid == 0) {
                float o = ob[0];
                #pragma unroll
                for (int k = 0; k < 16; k++) o += dh[k] * oW[k];
                ws[RECO + t] = o;
            }
            __syncthreads();
        }
    }
}

// ---- k_post: 4 elements per thread; fcW/rec/table staged in LDS ----
__global__ __launch_bounds__(256) void k_post(P29 a, const int* __restrict__ masks,
                                              const float* __restrict__ ws,
                                              float* __restrict__ out)
{
    __shared__ float tab[NTAB];
    __shared__ __align__(16) float fw[256];
    __shared__ __align__(16) float rec[16];
    __shared__ float fb[16];
    int tid = threadIdx.x;
    for (int i = tid; i < NTAB; i += 256) tab[i] = ws[TAB + i];
    fw[tid] = a.p[10][tid];
    if (tid < 16) { fb[tid] = a.p[11][tid]; rec[tid] = ws[RECO + tid]; }
    __syncthreads();
    int T = blockIdx.x * 256 + tid;
    int b = T >> 2;
    int q = T & 3;
    int tq = q * 4;
    const float4* hf4 = (const float4*)(ws + HFO + (size_t)b*16);
    const float4* hb4 = (const float4*)(ws + HBO + (size_t)b*16);
    float4 s0, s1, s2, s3;
    {
        float4 f0=hf4[0], f1=hf4[1], f2=hf4[2], f3=hf4[3];
        float4 g0=hb4[0], g1=hb4[1], g2=hb4[2], g3=hb4[3];
        s0 = make_float4(f0.x+g0.x, f0.y+g0.y, f0.z+g0.z, f0.w+g0.w);
        s1 = make_float4(f1.x+g1.x, f1.y+g1.y, f1.z+g1.z, f1.w+g1.w);
        s2 = make_float4(f2.x+g2.x, f2.y+g2.y, f2.z+g2.z, f2.w+g2.w);
        s3 = make_float4(f3.x+g3.x, f3.y+g3.y, f3.z+g3.z, f3.w+g3.w);
    }
    float4 hq = (q==0) ? s0 : (q==1) ? s1 : (q==2) ? s2 : s3;
    float4 xv = *(const float4*)(a.p[0] + (size_t)b*16 + tq);
    int4   mv = *(const int4*)(masks + (size_t)b*16 + tq);
    float impv[4];
    impv[0] = mv.x ? xv.x : hq.x;
    impv[1] = mv.y ? xv.y : hq.y;
    impv[2] = mv.z ? xv.z : hq.z;
    impv[3] = mv.w ? xv.w : hq.w;
    float latv[4];
    #pragma unroll
    for (int j = 0; j < 4; j++) {
        int t = tq + j;
        const float4* wr = (const float4*)(fw + t*16);
        float4 w0=wr[0], w1=wr[1], w2=wr[2], w3=wr[3];
        float l = fb[t];
        l += s0.x*w0.x + s0.y*w0.y + s0.z*w0.z + s0.w*w0.w;
        l += s1.x*w1.x + s1.y*w1.y + s1.z*w1.z + s1.w*w1.w;
        l += s2.x*w2.x + s2.y*w2.y + s2.z*w2.z + s2.w*w2.w;
        l += s3.x*w3.x + s3.y*w3.y + s3.z*w3.z + s3.w*w3.w;
        latv[j] = l;
    }
    float dv[4];
    #pragma unroll
    for (int j = 0; j < 4; j++) {
        float xx = fminf(fmaxf(impv[j], -8.f), 8.f);
        float f = (xx + 8.f) * 128.f;
        float fi = floorf(f);
        int i = (int)fi; i = i > NTAB-2 ? NTAB-2 : i;
        float w = f - fi;
        dv[j] = fmaf(w, tab[i+1] - tab[i], tab[i]);
    }
    float4 rv = ((const float4*)rec)[q];
    size_t eo = (size_t)b*16 + tq;
    *(float4*)(out + eo)        = make_float4(impv[0], impv[1], impv[2], impv[3]);
    *(float4*)(out + BS + eo)   = make_float4(dv[0], dv[1], dv[2], dv[3]);
    *(float4*)(out + 2*BS + eo) = make_float4(latv[0], latv[1], latv[2], latv[3]);
    *(float4*)(out + 3*BS + eo) = rv;
}

extern "C" void kernel_launch(void* const* d_in, const int* in_sizes, int n_in,
                              void* d_out, int out_size, void* d_ws, size_t ws_size,
                              hipStream_t stream)
{
    float* ws = (float*)d_ws;
    P29 a;
    for (int i = 0; i < 29; i++) a.p[i] = (const float*)d_in[i];
    const int* masks = (const int*)d_in[1];
    k_tabdec<<<130, 256, 0, stream>>>(a, ws);
    k_lstm<<<4096, 256, 0, stream>>>(a, masks, ws);
    k_post<<<(BB*4)/256, 256, 0, stream>>>(a, masks, ws, (float*)d_out);
}

// Round 12
// 180.627 us; speedup vs baseline: 1.0056x; 1.0056x over previous
//
#include <hip/hip_runtime.h>

#define BB 32768
#define BS (BB*16)   // 524288

typedef float v2f __attribute__((ext_vector_type(2)));

__device__ __forceinline__ v2f pk_fma(v2f a, v2f b, v2f c){
    v2f d;
    asm("v_pk_fma_f32 %0, %1, %2, %3" : "=v"(d) : "v"(a), "v"(b), "v"(c));
    return d;
}
__device__ __forceinline__ v2f pk_fma_lo(v2f a, v2f b, v2f c){  // both halves use a.lo
    v2f d;
    asm("v_pk_fma_f32 %0, %1, %2, %3 op_sel:[0,0,0] op_sel_hi:[0,1,1]"
        : "=v"(d) : "v"(a), "v"(b), "v"(c));
    return d;
}
__device__ __forceinline__ v2f pk_fma_hi(v2f a, v2f b, v2f c){  // both halves use a.hi
    v2f d;
    asm("v_pk_fma_f32 %0, %1, %2, %3 op_sel:[1,0,0] op_sel_hi:[1,1,1]"
        : "=v"(d) : "v"(a), "v"(b), "v"(c));
    return d;
}
// opacity barrier: an asm def cannot be rematerialized -> weights stay in VGPRs
__device__ __forceinline__ void pin2(v2f& a, v2f& b){
    asm("" : "+v"(a), "+v"(b));
}

// ---- ws float offsets ----
#define RECO 64
#define TAB  128             // disc F table, 2049 floats over [-8,8], step 1/128
#define NTAB 2049
#define HFO  8448
#define HBO  (HFO+BS)

// ---- table-kernel LDS layout ----
#define PW0 0
#define PB0 96
#define PW1 192
#define PB1 1920
#define PW2 1968
#define PB2 2448
#define PW3 2472
#define PB3 3048
#define PW4 3096
#define PB4 5016
#define POW 5112
#define POB 5144
#define PN  5148

__device__ __forceinline__ float sigm(float x){
    return __builtin_amdgcn_rcpf(1.f + __expf(-x));
}
__device__ __forceinline__ float tanh_f(float x){
    return 1.f - 2.f * __builtin_amdgcn_rcpf(1.f + __expf(2.f * x));
}
__device__ __forceinline__ float dunit(float gi, float gg, float go){
    return sigm(go) * tanh_f(sigm(gi) * tanh_f(gg));
}

struct P29 { const float* p[29]; };
// 0 values 1 masks 2-4 g_fwd(Wih,Whh,b) 5-7 g_bwd 8 impW 9 impb
// 10 fcW 11 fcb 12-14 dec(Wih,Whh,b) 15 dec_out_W 16 dec_out_b 17 disc_out_W
// 18 disc_out_b 19/20 d_W_0/d_b_0 ... 27/28 d_W_4/d_b_4

// ==== k_lstm: 16 lanes per (b,dir), 16 groups/block, 4.2KB LDS, weights
//      pinned in VGPRs via asm-opacity (r11: VGPR=60 proved remat). ====
__global__ __launch_bounds__(256)
void k_lstm(P29 a, const int* __restrict__ masks, float* __restrict__ ws)
{
    __shared__ __align__(16) float smem[1040];   // h: 16 sets x 48; x: 16 x 17
    int tid = threadIdx.x;
    int lane = tid & 63;
    int gbase = lane & 48;
    int u = tid & 15;
    int setw = tid >> 4;
    int gid = blockIdx.x * 16 + setw;            // 0..65535
    int dir = gid >> 15;
    int b = gid & 32767;
    const float* __restrict__ Whh = a.p[3 + 3*dir];
    v2f wif[16], wgo[16];
    #pragma unroll
    for (int q = 0; q < 4; q++) {
        float4 vi = ((const float4*)(Whh + (u)*16))[q];
        float4 vf = ((const float4*)(Whh + (16+u)*16))[q];
        float4 vg = ((const float4*)(Whh + (32+u)*16))[q];
        float4 vo = ((const float4*)(Whh + (48+u)*16))[q];
        wif[4*q+0] = (v2f){vi.x, vf.x}; wgo[4*q+0] = (v2f){vg.x, vo.x};
        wif[4*q+1] = (v2f){vi.y, vf.y}; wgo[4*q+1] = (v2f){vg.y, vo.y};
        wif[4*q+2] = (v2f){vi.z, vf.z}; wgo[4*q+2] = (v2f){vg.z, vo.z};
        wif[4*q+3] = (v2f){vi.w, vf.w}; wgo[4*q+3] = (v2f){vg.w, vo.w};
    }
    const float* __restrict__ Wih = a.p[2 + 3*dir];
    const float* __restrict__ bia = a.p[4 + 3*dir];
    v2f xif = (v2f){Wih[u], Wih[16+u]}, xgo = (v2f){Wih[32+u], Wih[48+u]};
    v2f bif = (v2f){bia[u], bia[16+u]}, bgo = (v2f){bia[32+u], bia[48+u]};
    v2f impw2[8];
    #pragma unroll
    for (int q = 0; q < 4; q++) {
        float4 v = ((const float4*)a.p[8])[q];
        impw2[2*q+0] = (v2f){v.x, v.y};
        impw2[2*q+1] = (v2f){v.z, v.w};
    }
    float impb = a.p[9][0];
    // ---- pin all hoisted weights (88 VGPRs) so they can't be rematerialized ----
    #pragma unroll
    for (int i = 0; i < 16; i++) pin2(wif[i], wgo[i]);
    #pragma unroll
    for (int i = 0; i < 8; i += 2) pin2(impw2[i], impw2[i+1]);
    pin2(xif, xgo);
    pin2(bif, bgo);
    float x_own = a.p[0][(size_t)b*16 + u];
    int   m_own = masks[(size_t)b*16 + u];
    unsigned mm = (unsigned)(__ballot(m_own != 0) >> gbase) & 0xffffu;
    int xo = 768 + setw*17;
    smem[xo + u] = x_own;
    // initial state: x=+/-128, h=c=0 (f-gate dead)
    float sgn = dir ? -128.f : 128.f;
    float giI = sgn*xif.x + bif.x, ggI = sgn*xgo.x + bgo.x, goI = sgn*xgo.y + bgo.y;
    float c = sigm(giI) * tanh_f(ggI);
    float h = sigm(goI) * tanh_f(c);
    int wa = setw*48 + u;
    int ra = setw*12;
    const float4* lhv = (const float4*)smem;
    #pragma unroll
    for (int t = 0; t < 16; t++) {
        smem[wa] = h;                            // DS in-order per wave
        float4 h0 = lhv[ra + 0];
        float4 h1 = lhv[ra + 1];
        float4 h2 = lhv[ra + 2];
        float4 h3 = lhv[ra + 3];
        v2f p0 = (v2f){h0.x, h0.y}, p1 = (v2f){h0.z, h0.w};
        v2f p2 = (v2f){h1.x, h1.y}, p3 = (v2f){h1.z, h1.w};
        v2f p4 = (v2f){h2.x, h2.y}, p5 = (v2f){h2.z, h2.w};
        v2f p6 = (v2f){h3.x, h3.y}, p7 = (v2f){h3.z, h3.w};
        v2f ia = (v2f){impb, 0.f};
        ia = pk_fma(p0, impw2[0], ia); ia = pk_fma(p1, impw2[1], ia);
        ia = pk_fma(p2, impw2[2], ia); ia = pk_fma(p3, impw2[3], ia);
        ia = pk_fma(p4, impw2[4], ia); ia = pk_fma(p5, impw2[5], ia);
        ia = pk_fma(p6, impw2[6], ia); ia = pk_fma(p7, impw2[7], ia);
        float imp = ia.x + ia.y;
        float xt = smem[xo + t];
        float cc = ((mm >> t) & 1u) ? imp : xt;
        v2f ccv = (v2f){cc, cc};
        v2f gif = pk_fma(ccv, xif, bif);
        v2f ggo = pk_fma(ccv, xgo, bgo);
        gif = pk_fma_lo(p0, wif[0],  gif); ggo = pk_fma_lo(p0, wgo[0],  ggo);
        gif = pk_fma_hi(p0, wif[1],  gif); ggo = pk_fma_hi(p0, wgo[1],  ggo);
        gif = pk_fma_lo(p1, wif[2],  gif); ggo = pk_fma_lo(p1, wgo[2],  ggo);
        gif = pk_fma_hi(p1, wif[3],  gif); ggo = pk_fma_hi(p1, wgo[3],  ggo);
        gif = pk_fma_lo(p2, wif[4],  gif); ggo = pk_fma_lo(p2, wgo[4],  ggo);
        gif = pk_fma_hi(p2, wif[5],  gif); ggo = pk_fma_hi(p2, wgo[5],  ggo);
        gif = pk_fma_lo(p3, wif[6],  gif); ggo = pk_fma_lo(p3, wgo[6],  ggo);
        gif = pk_fma_hi(p3, wif[7],  gif); ggo = pk_fma_hi(p3, wgo[7],  ggo);
        gif = pk_fma_lo(p4, wif[8],  gif); ggo = pk_fma_lo(p4, wgo[8],  ggo);
        gif = pk_fma_hi(p4, wif[9],  gif); ggo = pk_fma_hi(p4, wgo[9],  ggo);
        gif = pk_fma_lo(p5, wif[10], gif); ggo = pk_fma_lo(p5, wgo[10], ggo);
        gif = pk_fma_hi(p5, wif[11], gif); ggo = pk_fma_hi(p5, wgo[11], ggo);
        gif = pk_fma_lo(p6, wif[12], gif); ggo = pk_fma_lo(p6, wgo[12], ggo);
        gif = pk_fma_hi(p6, wif[13], gif); ggo = pk_fma_hi(p6, wgo[13], ggo);
        gif = pk_fma_lo(p7, wif[14], gif); ggo = pk_fma_lo(p7, wgo[14], ggo);
        gif = pk_fma_hi(p7, wif[15], gif); ggo = pk_fma_hi(p7, wgo[15], ggo);
        float cn = sigm(gif.y)*c + sigm(gif.x)*tanh_f(ggo.x);
        c = cn;
        h = sigm(ggo.y)*tanh_f(cn);
    }
    ws[HFO + (size_t)dir*BS + (size_t)b*16 + u] = h;
}

// ==== k_tabdec: blocks 0..128 = disc F table; block 129 = decoder scan ====
__global__ __launch_bounds__(256)
void k_tabdec(P29 a, float* __restrict__ ws)
{
    __shared__ __align__(16) float wl[PN];
    int tid = threadIdx.x;
    if (blockIdx.x < 129) {
#define STAGE(WS, BSi, h, K, padK, wdst, bdst) \
    { const float* Wp = a.p[WS]; const float* Bp = a.p[BSi]; \
      for (int i = tid; i < 3*(h)*(K); i += 256){ \
        int r = i/(K), k = i - r*(K); int g = r/(h), u0 = r - g*(h); \
        int sr = (g==0? u0 : (g==1? 2*(h)+u0 : 3*(h)+u0)); \
        wl[(wdst) + r*(padK) + k] = Wp[sr*(K) + k]; } \
      for (int i = tid; i < 3*(h); i += 256){ \
        int g = i/(h), u0 = i - g*(h); \
        int sr = (g==0? u0 : (g==1? 2*(h)+u0 : 3*(h)+u0)); \
        wl[(bdst) + i] = Bp[sr]; } }
        STAGE(19, 20, 32,  1,  1, PW0, PB0)
        STAGE(21, 22, 16, 32, 36, PW1, PB1)
        STAGE(23, 24,  8, 16, 20, PW2, PB2)
        STAGE(25, 26, 16,  8, 12, PW3, PB3)
        STAGE(27, 28, 32, 16, 20, PW4, PB4)
#undef STAGE
        { const float* s = a.p[17]; for (int i = tid; i < 32; i += 256) wl[POW+i] = s[i]; }
        if (tid == 0) wl[POB] = a.p[18][0];
        __syncthreads();
        int u = tid & 15;
        int gbase = (tid & 63) & 48;
        int gid = blockIdx.x * 16 + (tid >> 4);
        const float4* w4 = (const float4*)wl;
        float xin = -8.f + (float)gid * (1.f/128.f);
        float lo = dunit(xin*wl[PW0+u]    + wl[PB0+u],
                         xin*wl[PW0+32+u] + wl[PB0+32+u],
                         xin*wl[PW0+64+u] + wl[PB0+64+u]);
        float hi = dunit(xin*wl[PW0+16+u] + wl[PB0+16+u],
                         xin*wl[PW0+48+u] + wl[PB0+48+u],
                         xin*wl[PW0+80+u] + wl[PB0+80+u]);
        float A0[32];
        #pragma unroll
        for (int k = 0; k < 16; k++) { A0[k] = __shfl(lo, gbase+k); A0[16+k] = __shfl(hi, gbase+k); }
        float gi = wl[PB1+u], gg = wl[PB1+16+u], go = wl[PB1+32+u];
        int bi_ = (PW1 + u*36)>>2, bg_ = (PW1 + (16+u)*36)>>2, bo_ = (PW1 + (32+u)*36)>>2;
        #pragma unroll
        for (int q = 0; q < 8; q++) {
            float4 wi = w4[bi_+q], wg = w4[bg_+q], wo = w4[bo_+q];
            float b0=A0[4*q], b1=A0[4*q+1], b2=A0[4*q+2], b3=A0[4*q+3];
            gi += b0*wi.x + b1*wi.y + b2*wi.z + b3*wi.w;
            gg += b0*wg.x + b1*wg.y + b2*wg.z + b3*wg.w;
            go += b0*wo.x + b1*wo.y + b2*wo.z + b3*wo.w;
        }
        float a1 = dunit(gi, gg, go);
        float A1[16];
        #pragma unroll
        for (int k = 0; k < 16; k++) A1[k] = __shfl(a1, gbase+k);
        int v = u & 7;
        gi = wl[PB2+v]; gg = wl[PB2+8+v]; go = wl[PB2+16+v];
        bi_ = (PW2 + v*20)>>2; bg_ = (PW2 + (8+v)*20)>>2; bo_ = (PW2 + (16+v)*20)>>2;
        #pragma unroll
        for (int q = 0; q < 4; q++) {
            float4 wi = w4[bi_+q], wg = w4[bg_+q], wo = w4[bo_+q];
            float b0=A1[4*q], b1=A1[4*q+1], b2=A1[4*q+2], b3=A1[4*q+3];
            gi += b0*wi.x + b1*wi.y + b2*wi.z + b3*wi.w;
            gg += b0*wg.x + b1*wg.y + b2*wg.z + b3*wg.w;
            go += b0*wo.x + b1*wo.y + b2*wo.z + b3*wo.w;
        }
        float a2 = dunit(gi, gg, go);
        float A2[8];
        #pragma unroll
        for (int k = 0; k < 8; k++) A2[k] = __shfl(a2, gbase+k);
        gi = wl[PB3+u]; gg = wl[PB3+16+u]; go = wl[PB3+32+u];
        bi_ = (PW3 + u*12)>>2; bg_ = (PW3 + (16+u)*12)>>2; bo_ = (PW3 + (32+u)*12)>>2;
        #pragma unroll
        for (int q = 0; q < 2; q++) {
            float4 wi = w4[bi_+q], wg = w4[bg_+q], wo = w4[bo_+q];
            float b0=A2[4*q], b1=A2[4*q+1], b2=A2[4*q+2], b3=A2[4*q+3];
            gi += b0*wi.x + b1*wi.y + b2*wi.z + b3*wi.w;
            gg += b0*wg.x + b1*wg.y + b2*wg.z + b3*wg.w;
            go += b0*wo.x + b1*wo.y + b2*wo.z + b3*wo.w;
        }
        float a3 = dunit(gi, gg, go);
        float A3[16];
        #pragma unroll
        for (int k = 0; k < 16; k++) A3[k] = __shfl(a3, gbase+k);
        float part;
        {
            float g0i = wl[PB4+u], g0g = wl[PB4+32+u], g0o = wl[PB4+64+u];
            float g1i = wl[PB4+16+u], g1g = wl[PB4+48+u], g1o = wl[PB4+80+u];
            int c0i = (PW4 + u*20)>>2,      c0g = (PW4 + (32+u)*20)>>2, c0o = (PW4 + (64+u)*20)>>2;
            int c1i = (PW4 + (16+u)*20)>>2, c1g = (PW4 + (48+u)*20)>>2, c1o = (PW4 + (80+u)*20)>>2;
            #pragma unroll
            for (int q = 0; q < 4; q++) {
                float b0=A3[4*q], b1=A3[4*q+1], b2=A3[4*q+2], b3=A3[4*q+3];
                float4 wi = w4[c0i+q], wg = w4[c0g+q], wo = w4[c0o+q];
                g0i += b0*wi.x + b1*wi.y + b2*wi.z + b3*wi.w;
                g0g += b0*wg.x + b1*wg.y + b2*wg.z + b3*wg.w;
                g0o += b0*wo.x + b1*wo.y + b2*wo.z + b3*wo.w;
                wi = w4[c1i+q]; wg = w4[c1g+q]; wo = w4[c1o+q];
                g1i += b0*wi.x + b1*wi.y + b2*wi.z + b3*wi.w;
                g1g += b0*wg.x + b1*wg.y + b2*wg.z + b3*wg.w;
                g1o += b0*wo.x + b1*wo.y + b2*wo.z + b3*wo.w;
            }
            part = dunit(g0i, g0g, g0o)*wl[POW+u] + dunit(g1i, g1g, g1o)*wl[POW+16+u];
        }
        part += __shfl_xor(part, 1);
        part += __shfl_xor(part, 2);
        part += __shfl_xor(part, 4);
        part += __shfl_xor(part, 8);
        if (u == 0 && gid < NTAB) ws[TAB + gid] = part + wl[POB];
        return;
    }
    // ---------------- decoder block ----------------
    {
        float* dh = wl;
        float* dc = wl + 16;
        const float* Wih = a.p[12];
        const float* Whh = a.p[13];
        const float* bb  = a.p[14];
        const float* oW  = a.p[15];
        const float* ob  = a.p[16];
        float wii[16], wff[16], wgg[16], woo[16];
        float vii[16], vff[16], vgg[16], voo[16];
        float bi_r=0, bf_r=0, bg_r=0, bo_r=0;
        if (tid < 16) {
            int uu = tid;
            #pragma unroll
            for (int k = 0; k < 16; k++) {
                wii[k]=Wih[uu*16+k];      vii[k]=Whh[uu*16+k];
                wff[k]=Wih[(16+uu)*16+k]; vff[k]=Whh[(16+uu)*16+k];
                wgg[k]=Wih[(32+uu)*16+k]; vgg[k]=Whh[(32+uu)*16+k];
                woo[k]=Wih[(48+uu)*16+k]; voo[k]=Whh[(48+uu)*16+k];
            }
            bi_r=bb[uu]; bf_r=bb[16+uu]; bg_r=bb[32+uu]; bo_r=bb[48+uu];
            float gi = bi_r, gg = bg_r, go = bo_r;
            #pragma unroll
            for (int k = 0; k < 16; k++) {
                gi += 128.f * wii[k];
                gg += 128.f * wgg[k];
                go += 128.f * woo[k];
            }
            float c0 = sigm(gi) * tanh_f(gg);
            dc[tid] = c0; dh[tid] = sigm(go) * tanh_f(c0);
        }
        __syncthreads();
        for (int t = 0; t < 16; t++) {
            float rx[16], rh[16], cold = 0.f;
            if (tid < 16) {
                #pragma unroll
                for (int k = 0; k < 16; k++) { rx[k] = dc[k]; rh[k] = dh[k]; }
                cold = dc[tid];
            }
            __syncthreads();
            if (tid < 16) {
                float gi = bi_r, gf = bf_r, gg = bg_r, go = bo_r;
                #pragma unroll
                for (int k = 0; k < 16; k++) {
                    gi += rx[k]*wii[k] + rh[k]*vii[k];
                    gf += rx[k]*wff[k] + rh[k]*vff[k];
                    gg += rx[k]*wgg[k] + rh[k]*vgg[k];
                    go += rx[k]*woo[k] + rh[k]*voo[k];
                }
                float cn = sigm(gf)*cold + sigm(gi)*tanh_f(gg);
                dc[tid] = cn; dh[tid] = sigm(go)*tanh_f(cn);
            }
            __syncthreads();
            if (tid == 0) {
                float o = ob[0];
                #pragma unroll
                for (int k = 0; k < 16; k++) o += dh[k] * oW[k];
                ws[RECO + t] = o;
            }
            __syncthreads();
        }
    }
}

// ---- k_post: 4 elements per thread; fcW/rec/table staged in LDS ----
__global__ __launch_bounds__(256) void k_post(P29 a, const int* __restrict__ masks,
                                              const float* __restrict__ ws,
                                              float* __restrict__ out)
{
    __shared__ float tab[NTAB];
    __shared__ __align__(16) float fw[256];
    __shared__ __align__(16) float rec[16];
    __shared__ float fb[16];
    int tid = threadIdx.x;
    for (int i = tid; i < NTAB; i += 256) tab[i] = ws[TAB + i];
    fw[tid] = a.p[10][tid];
    if (tid < 16) { fb[tid] = a.p[11][tid]; rec[tid] = ws[RECO + tid]; }
    __syncthreads();
    int T = blockIdx.x * 256 + tid;
    int b = T >> 2;
    int q = T & 3;
    int tq = q * 4;
    const float4* hf4 = (const float4*)(ws + HFO + (size_t)b*16);
    const float4* hb4 = (const float4*)(ws + HBO + (size_t)b*16);
    float4 s0, s1, s2, s3;
    {
        float4 f0=hf4[0], f1=hf4[1], f2=hf4[2], f3=hf4[3];
        float4 g0=hb4[0], g1=hb4[1], g2=hb4[2], g3=hb4[3];
        s0 = make_float4(f0.x+g0.x, f0.y+g0.y, f0.z+g0.z, f0.w+g0.w);
        s1 = make_float4(f1.x+g1.x, f1.y+g1.y, f1.z+g1.z, f1.w+g1.w);
        s2 = make_float4(f2.x+g2.x, f2.y+g2.y, f2.z+g2.z, f2.w+g2.w);
        s3 = make_float4(f3.x+g3.x, f3.y+g3.y, f3.z+g3.z, f3.w+g3.w);
    }
    float4 hq = (q==0) ? s0 : (q==1) ? s1 : (q==2) ? s2 : s3;
    float4 xv = *(const float4*)(a.p[0] + (size_t)b*16 + tq);
    int4   mv = *(const int4*)(masks + (size_t)b*16 + tq);
    float impv[4];
    impv[0] = mv.x ? xv.x : hq.x;
    impv[1] = mv.y ? xv.y : hq.y;
    impv[2] = mv.z ? xv.z : hq.z;
    impv[3] = mv.w ? xv.w : hq.w;
    float latv[4];
    #pragma unroll
    for (int j = 0; j < 4; j++) {
        int t = tq + j;
        const float4* wr = (const float4*)(fw + t*16);
        float4 w0=wr[0], w1=wr[1], w2=wr[2], w3=wr[3];
        float l = fb[t];
        l += s0.x*w0.x + s0.y*w0.y + s0.z*w0.z + s0.w*w0.w;
        l += s1.x*w1.x + s1.y*w1.y + s1.z*w1.z + s1.w*w1.w;
        l += s2.x*w2.x + s2.y*w2.y + s2.z*w2.z + s2.w*w2.w;
        l += s3.x*w3.x + s3.y*w3.y + s3.z*w3.z + s3.w*w3.w;
        latv[j] = l;
    }
    float dv[4];
    #pragma unroll
    for (int j = 0; j < 4; j++) {
        float xx = fminf(fmaxf(impv[j], -8.f), 8.f);
        float f = (xx + 8.f) * 128.f;
        float fi = floorf(f);
        int i = (int)fi; i = i > NTAB-2 ? NTAB-2 : i;
        float w = f - fi;
        dv[j] = fmaf(w, tab[i+1] - tab[i], tab[i]);
    }
    float4 rv = ((const float4*)rec)[q];
    size_t eo = (size_t)b*16 + tq;
    *(float4*)(out + eo)        = make_float4(impv[0], impv[1], impv[2], impv[3]);
    *(float4*)(out + BS + eo)   = make_float4(dv[0], dv[1], dv[2], dv[3]);
    *(float4*)(out + 2*BS + eo) = make_float4(latv[0], latv[1], latv[2], latv[3]);
    *(float4*)(out + 3*BS + eo) = rv;
}

extern "C" void kernel_launch(void* const* d_in, const int* in_sizes, int n_in,
                              void* d_out, int out_size, void* d_ws, size_t ws_size,
                              hipStream_t stream)
{
    float* ws = (float*)d_ws;
    P29 a;
    for (int i = 0; i < 29; i++) a.p[i] = (const float*)d_in[i];
    const int* masks = (const int*)d_in[1];
    k_tabdec<<<130, 256, 0, stream>>>(a, ws);
    k_lstm<<<4096, 256, 0, stream>>>(a, masks, ws);
    k_post<<<(BB*4)/256, 256, 0, stream>>>(a, masks, ws, (float*)d_out);
}

// Round 13
// 165.859 us; speedup vs baseline: 1.0951x; 1.0890x over previous
//
#include <hip/hip_runtime.h>

#define BB 32768
#define BS (BB*16)   // 524288

typedef __attribute__((ext_vector_type(8))) short bf8v;   // 8 bf16 (4 VGPRs)
typedef __attribute__((ext_vector_type(4))) float f4v;

// ---- ws float offsets ----
#define RECO 64
#define TAB  128             // disc F table, 2049 floats over [-8,8], step 1/128
#define NTAB 2049
#define HFO  8448
#define HBO  (HFO+BS)

// ---- table-kernel LDS layout ----
#define PW0 0
#define PB0 96
#define PW1 192
#define PB1 1920
#define PW2 1968
#define PB2 2448
#define PW3 2472
#define PB3 3048
#define PW4 3096
#define PB4 5016
#define POW 5112
#define POB 5144
#define PN  5148

__device__ __forceinline__ float sigm(float x){
    return __builtin_amdgcn_rcpf(1.f + __expf(-x));
}
__device__ __forceinline__ float tanh_f(float x){
    return 1.f - 2.f * __builtin_amdgcn_rcpf(1.f + __expf(2.f * x));
}
__device__ __forceinline__ float dunit(float gi, float gg, float go){
    return sigm(go) * tanh_f(sigm(gi) * tanh_f(gg));
}
__device__ __forceinline__ unsigned short f2bf(float f){   // RNE
    union { float f; unsigned int i; } v; v.f = f;
    unsigned int x = v.i;
    unsigned int r = x + 0x7fffu + ((x >> 16) & 1u);
    return (unsigned short)(r >> 16);
}

struct P29 { const float* p[29]; };
// 0 values 1 masks 2-4 g_fwd(Wih,Whh,b) 5-7 g_bwd 8 impW 9 impb
// 10 fcW 11 fcb 12-14 dec(Wih,Whh,b) 15 dec_out_W 16 dec_out_b 17 disc_out_W
// 18 disc_out_b 19/20 d_W_0/d_b_0 ... 27/28 d_W_4/d_b_4

// B fragment for one gate: B[k=quad*8+j][n=lane&15]; rows of Whh (K=16),
// k=16 row = Wih column (cc term), k>16 = 0.
__device__ __forceinline__ bf8v makeB(const float* Whh, const float* Wih,
                                      int row, int quad)
{
    bf8v B = {0,0,0,0,0,0,0,0};
    if (quad < 2) {
        const float4* p = (const float4*)(Whh + row*16 + quad*8);
        float4 a0 = p[0], a1 = p[1];
        B[0]=(short)f2bf(a0.x); B[1]=(short)f2bf(a0.y);
        B[2]=(short)f2bf(a0.z); B[3]=(short)f2bf(a0.w);
        B[4]=(short)f2bf(a1.x); B[5]=(short)f2bf(a1.y);
        B[6]=(short)f2bf(a1.z); B[7]=(short)f2bf(a1.w);
    } else if (quad == 2) {
        B[0] = (short)f2bf(Wih[row]);
    }
    return B;
}

// ==== k_lstm: 16 groups per WAVE via bf16 MFMA; 4 waves/block, 1024 blocks.
//      B fragments = 20 VGPRs (nothing to spill — r7..r12 showed the
//      allocator refuses to keep 64+ weight VGPRs resident).
//      All LDS exchange is wave-private (in-order DS, no barriers). ====
__global__ __launch_bounds__(256)
void k_lstm(P29 a, const int* __restrict__ masks, float* __restrict__ ws)
{
    __shared__ __align__(16) float smem[2624];   // 4 waves x 656 floats
    int tid  = threadIdx.x;
    int lane = tid & 63;
    int wv   = tid >> 6;
    int n    = lane & 15;          // unit / A-row selector
    int quad = lane >> 4;
    int dir  = (int)(blockIdx.x >= 512);
    int gid0 = blockIdx.x * 64 + wv * 16;        // first group of this wave
    int b0   = gid0 & 32767;
    float* wbase = smem + wv * 656;
    float* xs    = wbase;                        // [t][m] 256
    int*   msI   = (int*)(wbase + 256);          // [t][m] 256
    unsigned short* hbp = (unsigned short*)(wbase + 512);  // h bf16 [m][u] 256
    float* ccf   = wbase + 640;                  // cc[m] 16
    const int4* hbI = (const int4*)hbp;

    // ---- stage x/mask transposed: [t][m] (wave-private, no barrier) ----
    {
        size_t gbase = (size_t)b0 * 16;
        int e = lane * 4;
        float4 xv = *(const float4*)(a.p[0] + gbase + e);
        int4   mv = *(const int4*)(masks + gbase + e);
        int sm = lane >> 2;           // m
        int st = (lane & 3) * 4;      // t base
        xs[(st+0)*16 + sm] = xv.x;  msI[(st+0)*16 + sm] = mv.x;
        xs[(st+1)*16 + sm] = xv.y;  msI[(st+1)*16 + sm] = mv.y;
        xs[(st+2)*16 + sm] = xv.z;  msI[(st+2)*16 + sm] = mv.z;
        xs[(st+3)*16 + sm] = xv.w;  msI[(st+3)*16 + sm] = mv.w;
    }
    const float* __restrict__ Wih = a.p[2 + 3*dir];
    const float* __restrict__ Whh = a.p[3 + 3*dir];
    const float* __restrict__ bia = a.p[4 + 3*dir];
    // B fragments (weights): 5 x 4 VGPRs
    bf8v Bi = makeB(Whh, Wih, n,      quad);
    bf8v Bf = makeB(Whh, Wih, 16+n,   quad);
    bf8v Bg = makeB(Whh, Wih, 32+n,   quad);
    bf8v Bo = makeB(Whh, Wih, 48+n,   quad);
    bf8v Bp = {0,0,0,0,0,0,0,0};                 // imp: B[k][n]=impw[k] all n
    if (quad < 2) {
        const float4* p = (const float4*)(a.p[8] + quad*8);
        float4 a0 = p[0], a1 = p[1];
        Bp[0]=(short)f2bf(a0.x); Bp[1]=(short)f2bf(a0.y);
        Bp[2]=(short)f2bf(a0.z); Bp[3]=(short)f2bf(a0.w);
        Bp[4]=(short)f2bf(a1.x); Bp[5]=(short)f2bf(a1.y);
        Bp[6]=(short)f2bf(a1.z); Bp[7]=(short)f2bf(a1.w);
    }
    float impb = a.p[9][0];
    float bi_ = bia[n], bf_ = bia[16+n], bg_ = bia[32+n], bo_ = bia[48+n];
    // initial state (x=+/-128, h=c=0 -> f gate dead); same for all groups
    float sgn = dir ? -128.f : 128.f;
    float c0, h0;
    {
        float gi0 = sgn*Wih[n]    + bi_;
        float gg0 = sgn*Wih[32+n] + bg_;
        float go0 = sgn*Wih[48+n] + bo_;
        c0 = sigm(gi0) * tanh_f(gg0);
        h0 = sigm(go0) * tanh_f(c0);
    }
    float c[4] = {c0, c0, c0, c0};
    float h[4];
    {
        unsigned short hb0 = f2bf(h0);
        #pragma unroll
        for (int r = 0; r < 4; r++) hbp[(quad*4+r)*16 + n] = hb0;
    }
    const f4v cz = {0.f, 0.f, 0.f, 0.f};
    const bf8v Az = {0,0,0,0,0,0,0,0};
    for (int t = 0; t < 16; t++) {
        // A fragment: A[m=n][k=quad*8+j] = h_bf16; quads 2,3 zero (cc later)
        union { int4 i4; bf8v b; } au;
        au.i4 = hbI[(n << 1) | (quad & 1)];
        bf8v A = (quad < 2) ? au.b : Az;
        // imp for all 16 groups: lane gets rows m=quad*4+r
        f4v dimp = __builtin_amdgcn_mfma_f32_16x16x32_bf16(A, Bp, cz, 0, 0, 0);
        float4 xt4 = *(const float4*)(xs + t*16 + quad*4);
        int4   mt4 = *(const int4*)(msI + t*16 + quad*4);
        float cc0 = mt4.x ? (dimp[0] + impb) : xt4.x;
        float cc1 = mt4.y ? (dimp[1] + impb) : xt4.y;
        float cc2 = mt4.z ? (dimp[2] + impb) : xt4.z;
        float cc3 = mt4.w ? (dimp[3] + impb) : xt4.w;
        if (n == 0) {
            ccf[quad*4+0] = cc0; ccf[quad*4+1] = cc1;
            ccf[quad*4+2] = cc2; ccf[quad*4+3] = cc3;
        }
        // insert cc at k=16 (quad 2, j=0); DS in-order within wave
        if (quad == 2) A[0] = (short)f2bf(ccf[n]);
        f4v di = __builtin_amdgcn_mfma_f32_16x16x32_bf16(A, Bi, cz, 0, 0, 0);
        f4v df = __builtin_amdgcn_mfma_f32_16x16x32_bf16(A, Bf, cz, 0, 0, 0);
        f4v dg = __builtin_amdgcn_mfma_f32_16x16x32_bf16(A, Bg, cz, 0, 0, 0);
        f4v dO = __builtin_amdgcn_mfma_f32_16x16x32_bf16(A, Bo, cz, 0, 0, 0);
        #pragma unroll
        for (int r = 0; r < 4; r++) {
            float gi = di[r] + bi_;
            float gf = df[r] + bf_;
            float gg = dg[r] + bg_;
            float go = dO[r] + bo_;
            float cn = sigm(gf)*c[r] + sigm(gi)*tanh_f(gg);
            c[r] = cn;
            float hh = sigm(go)*tanh_f(cn);
            h[r] = hh;
            hbp[(quad*4+r)*16 + n] = f2bf(hh);
        }
    }
    float* outp = ws + HFO + (size_t)dir*BS + (size_t)b0*16;
    #pragma unroll
    for (int r = 0; r < 4; r++) outp[(quad*4+r)*16 + n] = h[r];
}

// ==== k_tabdec: blocks 0..128 = disc F table; block 129 = decoder scan ====
__global__ __launch_bounds__(256)
void k_tabdec(P29 a, float* __restrict__ ws)
{
    __shared__ __align__(16) float wl[PN];
    int tid = threadIdx.x;
    if (blockIdx.x < 129) {
#define STAGE(WS, BSi, h, K, padK, wdst, bdst) \
    { const float* Wp = a.p[WS]; const float* Bp2 = a.p[BSi]; \
      for (int i = tid; i < 3*(h)*(K); i += 256){ \
        int r = i/(K), k = i - r*(K); int g = r/(h), u0 = r - g*(h); \
        int sr = (g==0? u0 : (g==1? 2*(h)+u0 : 3*(h)+u0)); \
        wl[(wdst) + r*(padK) + k] = Wp[sr*(K) + k]; } \
      for (int i = tid; i < 3*(h); i += 256){ \
        int g = i/(h), u0 = i - g*(h); \
        int sr = (g==0? u0 : (g==1? 2*(h)+u0 : 3*(h)+u0)); \
        wl[(bdst) + i] = Bp2[sr]; } }
        STAGE(19, 20, 32,  1,  1, PW0, PB0)
        STAGE(21, 22, 16, 32, 36, PW1, PB1)
        STAGE(23, 24,  8, 16, 20, PW2, PB2)
        STAGE(25, 26, 16,  8, 12, PW3, PB3)
        STAGE(27, 28, 32, 16, 20, PW4, PB4)
#undef STAGE
        { const float* s = a.p[17]; for (int i = tid; i < 32; i += 256) wl[POW+i] = s[i]; }
        if (tid == 0) wl[POB] = a.p[18][0];
        __syncthreads();
        int u = tid & 15;
        int gbase = (tid & 63) & 48;
        int gid = blockIdx.x * 16 + (tid >> 4);
        const float4* w4 = (const float4*)wl;
        float xin = -8.f + (float)gid * (1.f/128.f);
        float lo = dunit(xin*wl[PW0+u]    + wl[PB0+u],
                         xin*wl[PW0+32+u] + wl[PB0+32+u],
                         xin*wl[PW0+64+u] + wl[PB0+64+u]);
        float hi = dunit(xin*wl[PW0+16+u] + wl[PB0+16+u],
                         xin*wl[PW0+48+u] + wl[PB0+48+u],
                         xin*wl[PW0+80+u] + wl[PB0+80+u]);
        float A0[32];
        #pragma unroll
        for (int k = 0; k < 16; k++) { A0[k] = __shfl(lo, gbase+k); A0[16+k] = __shfl(hi, gbase+k); }
        float gi = wl[PB1+u], gg = wl[PB1+16+u], go = wl[PB1+32+u];
        int bi_ = (PW1 + u*36)>>2, bg_ = (PW1 + (16+u)*36)>>2, bo_ = (PW1 + (32+u)*36)>>2;
        #pragma unroll
        for (int q = 0; q < 8; q++) {
            float4 wi = w4[bi_+q], wg = w4[bg_+q], wo = w4[bo_+q];
            float b0=A0[4*q], b1=A0[4*q+1], b2=A0[4*q+2], b3=A0[4*q+3];
            gi += b0*wi.x + b1*wi.y + b2*wi.z + b3*wi.w;
            gg += b0*wg.x + b1*wg.y + b2*wg.z + b3*wg.w;
            go += b0*wo.x + b1*wo.y + b2*wo.z + b3*wo.w;
        }
        float a1 = dunit(gi, gg, go);
        float A1[16];
        #pragma unroll
        for (int k = 0; k < 16; k++) A1[k] = __shfl(a1, gbase+k);
        int v = u & 7;
        gi = wl[PB2+v]; gg = wl[PB2+8+v]; go = wl[PB2+16+v];
        bi_ = (PW2 + v*20)>>2; bg_ = (PW2 + (8+v)*20)>>2; bo_ = (PW2 + (16+v)*20)>>2;
        #pragma unroll
        for (int q = 0; q < 4; q++) {
            float4 wi = w4[bi_+q], wg = w4[bg_+q], wo = w4[bo_+q];
            float b0=A1[4*q], b1=A1[4*q+1], b2=A1[4*q+2], b3=A1[4*q+3];
            gi += b0*wi.x + b1*wi.y + b2*wi.z + b3*wi.w;
            gg += b0*wg.x + b1*wg.y + b2*wg.z + b3*wg.w;
            go += b0*wo.x + b1*wo.y + b2*wo.z + b3*wo.w;
        }
        float a2 = dunit(gi, gg, go);
        float A2[8];
        #pragma unroll
        for (int k = 0; k < 8; k++) A2[k] = __shfl(a2, gbase+k);
        gi = wl[PB3+u]; gg = wl[PB3+16+u]; go = wl[PB3+32+u];
        bi_ = (PW3 + u*12)>>2; bg_ = (PW3 + (16+u)*12)>>2; bo_ = (PW3 + (32+u)*12)>>2;
        #pragma unroll
        for (int q = 0; q < 2; q++) {
            float4 wi = w4[bi_+q], wg = w4[bg_+q], wo = w4[bo_+q];
            float b0=A2[4*q], b1=A2[4*q+1], b2=A2[4*q+2], b3=A2[4*q+3];
            gi += b0*wi.x + b1*wi.y + b2*wi.z + b3*wi.w;
            gg += b0*wg.x + b1*wg.y + b2*wg.z + b3*wg.w;
            go += b0*wo.x + b1*wo.y + b2*wo.z + b3*wo.w;
        }
        float a3 = dunit(gi, gg, go);
        float A3[16];
        #pragma unroll
        for (int k = 0; k < 16; k++) A3[k] = __shfl(a3, gbase+k);
        float part;
        {
            float g0i = wl[PB4+u], g0g = wl[PB4+32+u], g0o = wl[PB4+64+u];
            float g1i = wl[PB4+16+u], g1g = wl[PB4+48+u], g1o = wl[PB4+80+u];
            int c0i = (PW4 + u*20)>>2,      c0g = (PW4 + (32+u)*20)>>2, c0o = (PW4 + (64+u)*20)>>2;
            int c1i = (PW4 + (16+u)*20)>>2, c1g = (PW4 + (48+u)*20)>>2, c1o = (PW4 + (80+u)*20)>>2;
            #pragma unroll
            for (int q = 0; q < 4; q++) {
                float b0=A3[4*q], b1=A3[4*q+1], b2=A3[4*q+2], b3=A3[4*q+3];
                float4 wi = w4[c0i+q], wg = w4[c0g+q], wo = w4[c0o+q];
                g0i += b0*wi.x + b1*wi.y + b2*wi.z + b3*wi.w;
                g0g += b0*wg.x + b1*wg.y + b2*wg.z + b3*wg.w;
                g0o += b0*wo.x + b1*wo.y + b2*wo.z + b3*wo.w;
                wi = w4[c1i+q]; wg = w4[c1g+q]; wo = w4[c1o+q];
                g1i += b0*wi.x + b1*wi.y + b2*wi.z + b3*wi.w;
                g1g += b0*wg.x + b1*wg.y + b2*wg.z + b3*wg.w;
                g1o += b0*wo.x + b1*wo.y + b2*wo.z + b3*wo.w;
            }
            part = dunit(g0i, g0g, g0o)*wl[POW+u] + dunit(g1i, g1g, g1o)*wl[POW+16+u];
        }
        part += __shfl_xor(part, 1);
        part += __shfl_xor(part, 2);
        part += __shfl_xor(part, 4);
        part += __shfl_xor(part, 8);
        if (u == 0 && gid < NTAB) ws[TAB + gid] = part + wl[POB];
        return;
    }
    // ---------------- decoder block ----------------
    {
        float* dh = wl;
        float* dc = wl + 16;
        const float* Wih = a.p[12];
        const float* Whh = a.p[13];
        const float* bb  = a.p[14];
        const float* oW  = a.p[15];
        const float* ob  = a.p[16];
        float wii[16], wff[16], wgg[16], woo[16];
        float vii[16], vff[16], vgg[16], voo[16];
        float bi_r=0, bf_r=0, bg_r=0, bo_r=0;
        if (tid < 16) {
            int uu = tid;
            #pragma unroll
            for (int k = 0; k < 16; k++) {
                wii[k]=Wih[uu*16+k];      vii[k]=Whh[uu*16+k];
                wff[k]=Wih[(16+uu)*16+k]; vff[k]=Whh[(16+uu)*16+k];
                wgg[k]=Wih[(32+uu)*16+k]; vgg[k]=Whh[(32+uu)*16+k];
                woo[k]=Wih[(48+uu)*16+k]; voo[k]=Whh[(48+uu)*16+k];
            }
            bi_r=bb[uu]; bf_r=bb[16+uu]; bg_r=bb[32+uu]; bo_r=bb[48+uu];
            float gi = bi_r, gg = bg_r, go = bo_r;
            #pragma unroll
            for (int k = 0; k < 16; k++) {
                gi += 128.f * wii[k];
                gg += 128.f * wgg[k];
                go += 128.f * woo[k];
            }
            float cd0 = sigm(gi) * tanh_f(gg);
            dc[tid] = cd0; dh[tid] = sigm(go) * tanh_f(cd0);
        }
        __syncthreads();
        for (int t = 0; t < 16; t++) {
            float rx[16], rh[16], cold = 0.f;
            if (tid < 16) {
                #pragma unroll
                for (int k = 0; k < 16; k++) { rx[k] = dc[k]; rh[k] = dh[k]; }
                cold = dc[tid];
            }
            __syncthreads();
            if (tid < 16) {
                float gi = bi_r, gf = bf_r, gg = bg_r, go = bo_r;
                #pragma unroll
                for (int k = 0; k < 16; k++) {
                    gi += rx[k]*wii[k] + rh[k]*vii[k];
                    gf += rx[k]*wff[k] + rh[k]*vff[k];
                    gg += rx[k]*wgg[k] + rh[k]*vgg[k];
                    go += rx[k]*woo[k] + rh[k]*voo[k];
                }
                float cn = sigm(gf)*cold + sigm(gi)*tanh_f(gg);
                dc[tid] = cn; dh[tid] = sigm(go)*tanh_f(cn);
            }
            __syncthreads();
            if (tid == 0) {
                float o = ob[0];
                #pragma unroll
                for (int k = 0; k < 16; k++) o += dh[k] * oW[k];
                ws[RECO + t] = o;
            }
            __syncthreads();
        }
    }
}

// ---- k_post: 4 elements per thread; fcW/rec/table staged in LDS ----
__global__ __launch_bounds__(256) void k_post(P29 a, const int* __restrict__ masks,
                                              const float* __restrict__ ws,
                                              float* __restrict__ out)
{
    __shared__ float tab[NTAB];
    __shared__ __align__(16) float fw[256];
    __shared__ __align__(16) float rec[16];
    __shared__ float fb[16];
    int tid = threadIdx.x;
    for (int i = tid; i < NTAB; i += 256) tab[i] = ws[TAB + i];
    fw[tid] = a.p[10][tid];
    if (tid < 16) { fb[tid] = a.p[11][tid]; rec[tid] = ws[RECO + tid]; }
    __syncthreads();
    int T = blockIdx.x * 256 + tid;
    int b = T >> 2;
    int q = T & 3;
    int tq = q * 4;
    const float4* hf4 = (const float4*)(ws + HFO + (size_t)b*16);
    const float4* hb4 = (const float4*)(ws + HBO + (size_t)b*16);
    float4 s0, s1, s2, s3;
    {
        float4 f0=hf4[0], f1=hf4[1], f2=hf4[2], f3=hf4[3];
        float4 g0=hb4[0], g1=hb4[1], g2=hb4[2], g3=hb4[3];
        s0 = make_float4(f0.x+g0.x, f0.y+g0.y, f0.z+g0.z, f0.w+g0.w);
        s1 = make_float4(f1.x+g1.x, f1.y+g1.y, f1.z+g1.z, f1.w+g1.w);
        s2 = make_float4(f2.x+g2.x, f2.y+g2.y, f2.z+g2.z, f2.w+g2.w);
        s3 = make_float4(f3.x+g3.x, f3.y+g3.y, f3.z+g3.z, f3.w+g3.w);
    }
    float4 hq = (q==0) ? s0 : (q==1) ? s1 : (q==2) ? s2 : s3;
    float4 xv = *(const float4*)(a.p[0] + (size_t)b*16 + tq);
    int4   mv = *(const int4*)(masks + (size_t)b*16 + tq);
    float impv[4];
    impv[0] = mv.x ? xv.x : hq.x;
    impv[1] = mv.y ? xv.y : hq.y;
    impv[2] = mv.z ? xv.z : hq.z;
    impv[3] = mv.w ? xv.w : hq.w;
    float latv[4];
    #pragma unroll
    for (int j = 0; j < 4; j++) {
        int t = tq + j;
        const float4* wr = (const float4*)(fw + t*16);
        float4 w0=wr[0], w1=wr[1], w2=wr[2], w3=wr[3];
        float l = fb[t];
        l += s0.x*w0.x + s0.y*w0.y + s0.z*w0.z + s0.w*w0.w;
        l += s1.x*w1.x + s1.y*w1.y + s1.z*w1.z + s1.w*w1.w;
        l += s2.x*w2.x + s2.y*w2.y + s2.z*w2.z + s2.w*w2.w;
        l += s3.x*w3.x + s3.y*w3.y + s3.z*w3.z + s3.w*w3.w;
        latv[j] = l;
    }
    float dv[4];
    #pragma unroll
    for (int j = 0; j < 4; j++) {
        float xx = fminf(fmaxf(impv[j], -8.f), 8.f);
        float f = (xx + 8.f) * 128.f;
        float fi = floorf(f);
        int i = (int)fi; i = i > NTAB-2 ? NTAB-2 : i;
        float w = f - fi;
        dv[j] = fmaf(w, tab[i+1] - tab[i], tab[i]);
    }
    float4 rv = ((const float4*)rec)[q];
    size_t eo = (size_t)b*16 + tq;
    *(float4*)(out + eo)        = make_float4(impv[0], impv[1], impv[2], impv[3]);
    *(float4*)(out + BS + eo)   = make_float4(dv[0], dv[1], dv[2], dv[3]);
    *(float4*)(out + 2*BS + eo) = make_float4(latv[0], latv[1], latv[2], latv[3]);
    *(float4*)(out + 3*BS + eo) = rv;
}

extern "C" void kernel_launch(void* const* d_in, const int* in_sizes, int n_in,
                              void* d_out, int out_size, void* d_ws, size_t ws_size,
                              hipStream_t stream)
{
    float* ws = (float*)d_ws;
    P29 a;
    for (int i = 0; i < 29; i++) a.p[i] = (const float*)d_in[i];
    const int* masks = (const int*)d_in[1];
    k_tabdec<<<130, 256, 0, stream>>>(a, ws);
    k_lstm<<<1024, 256, 0, stream>>>(a, masks, ws);   // 64 groups/block via MFMA
    k_post<<<(BB*4)/256, 256, 0, stream>>>(a, masks, ws, (float*)d_out);
}

// Round 14
// 163.754 us; speedup vs baseline: 1.1092x; 1.0128x over previous
//
#include <hip/hip_runtime.h>

#define BB 32768
#define BS (BB*16)   // 524288

typedef __attribute__((ext_vector_type(8))) short bf8v;   // 8 bf16 (4 VGPRs)
typedef __attribute__((ext_vector_type(4))) float f4v;

// ---- ws float offsets ----
#define RECO 64
#define TAB  128             // disc F table, 2049 floats over [-8,8], step 1/128
#define NTAB 2049

// ---- table-kernel LDS layout ----
#define PW0 0
#define PB0 96
#define PW1 192
#define PB1 1920
#define PW2 1968
#define PB2 2448
#define PW3 2472
#define PB3 3048
#define PW4 3096
#define PB4 5016
#define POW 5112
#define POB 5144
#define PN  5148

__device__ __forceinline__ float sigm(float x){
    return __builtin_amdgcn_rcpf(1.f + __expf(-x));
}
__device__ __forceinline__ float tanh_f(float x){
    return 1.f - 2.f * __builtin_amdgcn_rcpf(1.f + __expf(2.f * x));
}
__device__ __forceinline__ float dunit(float gi, float gg, float go){
    return sigm(go) * tanh_f(sigm(gi) * tanh_f(gg));
}
__device__ __forceinline__ unsigned short f2bf(float f){   // RNE
    union { float f; unsigned int i; } v; v.f = f;
    unsigned int x = v.i;
    unsigned int r = x + 0x7fffu + ((x >> 16) & 1u);
    return (unsigned short)(r >> 16);
}

struct P29 { const float* p[29]; };
// 0 values 1 masks 2-4 g_fwd(Wih,Whh,b) 5-7 g_bwd 8 impW 9 impb
// 10 fcW 11 fcb 12-14 dec(Wih,Whh,b) 15 dec_out_W 16 dec_out_b 17 disc_out_W
// 18 disc_out_b 19/20 d_W_0/d_b_0 ... 27/28 d_W_4/d_b_4

// B fragment for one gate: B[k=quad*8+j][n]; k<16 = Whh row, k=16 = Wih (cc), else 0.
// Layout HW-validated in r13 (absmax 1.95e-3).
__device__ __forceinline__ bf8v makeB(const float* Whh, const float* Wih,
                                      int row, int quad)
{
    bf8v B = {0,0,0,0,0,0,0,0};
    if (quad < 2) {
        const float4* p = (const float4*)(Whh + row*16 + quad*8);
        float4 a0 = p[0], a1 = p[1];
        B[0]=(short)f2bf(a0.x); B[1]=(short)f2bf(a0.y);
        B[2]=(short)f2bf(a0.z); B[3]=(short)f2bf(a0.w);
        B[4]=(short)f2bf(a1.x); B[5]=(short)f2bf(a1.y);
        B[6]=(short)f2bf(a1.z); B[7]=(short)f2bf(a1.w);
    } else if (quad == 2) {
        B[0] = (short)f2bf(Wih[row]);
    }
    return B;
}

// ==== k_fused: one wave = 8 batches x BOTH dirs (rows 0-7 fwd, 8-15 bwd).
//      MFMA scan + inline epilogue (imputed/latent/disc-lerp/rec -> d_out).
//      All LDS traffic wave-private (in-order DS, no barriers). ====
__global__ __launch_bounds__(256)
void k_fused(P29 a, const int* __restrict__ masks, const float* __restrict__ ws,
             float* __restrict__ out)
{
    __shared__ __align__(16) float smem[4*784];
    int tid  = threadIdx.x;
    int lane = tid & 63;
    int wv   = tid >> 6;
    int n    = lane & 15;          // unit / column
    int quad = lane >> 4;
    int mydir = (quad >= 2);       // rows quad*4+r: quads 0,1 = fwd, 2,3 = bwd
    int b0   = (blockIdx.x * 4 + wv) * 8;        // first batch of this wave
    float* W = smem + wv * 784;
    float* xs  = W;                               // [t][b8] 128
    int*   msI = (int*)(W + 128);                 // [t][b8] 128
    unsigned short* hbp = (unsigned short*)(W + 256);  // h bf16 [m16][u16]
    float* ccf = W + 384;                         // cc[m] 16
    float* hsf = W + 400;                         // h fp32 [m16][u16] 256
    float* hsm = W + 656;                         // h_f+h_b [b8][u16] 128
    const int4* hbI = (const int4*)hbp;

    // ---- stage x/mask transposed [t][b] (lanes 0..31; wave-private) ----
    if (lane < 32) {
        size_t g = (size_t)b0 * 16 + lane * 4;
        float4 xv = *(const float4*)(a.p[0] + g);
        int4   mv = *(const int4*)(masks + g);
        int bl = lane >> 2;
        int t0 = (lane & 3) * 4;
        xs[(t0+0)*8 + bl] = xv.x;  msI[(t0+0)*8 + bl] = mv.x;
        xs[(t0+1)*8 + bl] = xv.y;  msI[(t0+1)*8 + bl] = mv.y;
        xs[(t0+2)*8 + bl] = xv.z;  msI[(t0+2)*8 + bl] = mv.z;
        xs[(t0+3)*8 + bl] = xv.w;  msI[(t0+3)*8 + bl] = mv.w;
    }
    const float* __restrict__ WihF = a.p[2];
    const float* __restrict__ WhhF = a.p[3];
    const float* __restrict__ WihB = a.p[5];
    const float* __restrict__ WhhB = a.p[6];
    // B fragments: 4 gates x 2 dirs + imp = 9 x 4 VGPRs
    bf8v BiF = makeB(WhhF, WihF, n,    quad);
    bf8v BfF = makeB(WhhF, WihF, 16+n, quad);
    bf8v BgF = makeB(WhhF, WihF, 32+n, quad);
    bf8v BoF = makeB(WhhF, WihF, 48+n, quad);
    bf8v BiB = makeB(WhhB, WihB, n,    quad);
    bf8v BfB = makeB(WhhB, WihB, 16+n, quad);
    bf8v BgB = makeB(WhhB, WihB, 32+n, quad);
    bf8v BoB = makeB(WhhB, WihB, 48+n, quad);
    bf8v Bp = {0,0,0,0,0,0,0,0};                 // imp: B[k][n]=impw[k], all n
    if (quad < 2) {
        const float4* p = (const float4*)(a.p[8] + quad*8);
        float4 a0 = p[0], a1 = p[1];
        Bp[0]=(short)f2bf(a0.x); Bp[1]=(short)f2bf(a0.y);
        Bp[2]=(short)f2bf(a0.z); Bp[3]=(short)f2bf(a0.w);
        Bp[4]=(short)f2bf(a1.x); Bp[5]=(short)f2bf(a1.y);
        Bp[6]=(short)f2bf(a1.z); Bp[7]=(short)f2bf(a1.w);
    }
    float impb = a.p[9][0];
    const float* biaMy = a.p[4 + 3*mydir];
    const float* WihMy = mydir ? WihB : WihF;
    float bi_ = biaMy[n], bf_ = biaMy[16+n], bg_ = biaMy[32+n], bo_ = biaMy[48+n];
    // initial state (x=+/-128, h=c=0 -> f gate dead); per-dir
    float sgn = mydir ? -128.f : 128.f;
    float c0, h0;
    {
        float gi0 = sgn*WihMy[n]    + bi_;
        float gg0 = sgn*WihMy[32+n] + bg_;
        float go0 = sgn*WihMy[48+n] + bo_;
        c0 = sigm(gi0) * tanh_f(gg0);
        h0 = sigm(go0) * tanh_f(c0);
    }
    float c[4] = {c0, c0, c0, c0};
    float h[4];
    {
        unsigned short hb0 = f2bf(h0);
        #pragma unroll
        for (int r = 0; r < 4; r++) hbp[(quad*4+r)*16 + n] = hb0;
    }
    const f4v cz = {0.f, 0.f, 0.f, 0.f};
    const bf8v Az = {0,0,0,0,0,0,0,0};
    for (int t = 0; t < 16; t++) {
        union { int4 i4; bf8v b; } au;
        au.i4 = hbI[(n << 1) | (quad & 1)];
        bf8v A = (quad < 2) ? au.b : Az;
        f4v dimp = __builtin_amdgcn_mfma_f32_16x16x32_bf16(A, Bp, cz, 0, 0, 0);
        float4 xt4 = *(const float4*)(xs + t*8 + (quad & 1)*4);
        int4   mt4 = *(const int4*)(msI + t*8 + (quad & 1)*4);
        float cc0 = mt4.x ? (dimp[0] + impb) : xt4.x;
        float cc1 = mt4.y ? (dimp[1] + impb) : xt4.y;
        float cc2 = mt4.z ? (dimp[2] + impb) : xt4.z;
        float cc3 = mt4.w ? (dimp[3] + impb) : xt4.w;
        if (n == 0) {
            ccf[quad*4+0] = cc0; ccf[quad*4+1] = cc1;
            ccf[quad*4+2] = cc2; ccf[quad*4+3] = cc3;
        }
        if (quad == 2) A[0] = (short)f2bf(ccf[n]);   // cc at k=16
        f4v diF = __builtin_amdgcn_mfma_f32_16x16x32_bf16(A, BiF, cz, 0, 0, 0);
        f4v dfF = __builtin_amdgcn_mfma_f32_16x16x32_bf16(A, BfF, cz, 0, 0, 0);
        f4v dgF = __builtin_amdgcn_mfma_f32_16x16x32_bf16(A, BgF, cz, 0, 0, 0);
        f4v doF = __builtin_amdgcn_mfma_f32_16x16x32_bf16(A, BoF, cz, 0, 0, 0);
        f4v diB = __builtin_amdgcn_mfma_f32_16x16x32_bf16(A, BiB, cz, 0, 0, 0);
        f4v dfB = __builtin_amdgcn_mfma_f32_16x16x32_bf16(A, BfB, cz, 0, 0, 0);
        f4v dgB = __builtin_amdgcn_mfma_f32_16x16x32_bf16(A, BgB, cz, 0, 0, 0);
        f4v doB = __builtin_amdgcn_mfma_f32_16x16x32_bf16(A, BoB, cz, 0, 0, 0);
        #pragma unroll
        for (int r = 0; r < 4; r++) {
            float gi = (mydir ? diB[r] : diF[r]) + bi_;
            float gf = (mydir ? dfB[r] : dfF[r]) + bf_;
            float gg = (mydir ? dgB[r] : dgF[r]) + bg_;
            float go = (mydir ? doB[r] : doF[r]) + bo_;
            float cn = sigm(gf)*c[r] + sigm(gi)*tanh_f(gg);
            c[r] = cn;
            float hh = sigm(go)*tanh_f(cn);
            h[r] = hh;
            hbp[(quad*4+r)*16 + n] = f2bf(hh);
        }
    }
    // ---- epilogue: hs = h_f + h_b, then per-(b,t) outputs ----
    #pragma unroll
    for (int r = 0; r < 4; r++) hsf[(quad*4+r)*16 + n] = h[r];
    if (quad < 2) {
        #pragma unroll
        for (int r = 0; r < 4; r++) {
            int m = quad*4 + r;
            hsm[m*16 + n] = hsf[m*16 + n] + hsf[(m+8)*16 + n];
        }
    }
    size_t gbase = (size_t)b0 * 16;
    #pragma unroll
    for (int half = 0; half < 2; half++) {
        int e = half*64 + lane;
        int bl = e >> 4, t = e & 15;
        float x  = xs[t*8 + bl];
        int   mk = msI[t*8 + bl];
        float imputed = mk ? x : hsm[e];
        // latent: hs[bl] . fcW[t,:] + fc_b[t]
        const float4* hr = (const float4*)(hsm + bl*16);
        const float4* wr = (const float4*)(a.p[10] + t*16);
        float4 s0=hr[0], s1=hr[1], s2=hr[2], s3=hr[3];
        float4 w0=wr[0], w1=wr[1], w2=wr[2], w3=wr[3];
        float lat = a.p[11][t];
        lat += s0.x*w0.x + s0.y*w0.y + s0.z*w0.z + s0.w*w0.w;
        lat += s1.x*w1.x + s1.y*w1.y + s1.z*w1.z + s1.w*w1.w;
        lat += s2.x*w2.x + s2.y*w2.y + s2.z*w2.z + s2.w*w2.w;
        lat += s3.x*w3.x + s3.y*w3.y + s3.z*w3.z + s3.w*w3.w;
        // disc via table lerp (table in ws, L2-resident)
        float xx = fminf(fmaxf(imputed, -8.f), 8.f);
        float f = (xx + 8.f) * 128.f;
        float fi = floorf(f);
        int i = (int)fi; i = i > NTAB-2 ? NTAB-2 : i;
        float wgt = f - fi;
        float t0v = ws[TAB + i], t1v = ws[TAB + i + 1];
        float dv = fmaf(wgt, t1v - t0v, t0v);
        float rv = ws[RECO + t];
        out[gbase + e]        = imputed;
        out[BS + gbase + e]   = dv;
        out[2*BS + gbase + e] = lat;
        out[3*BS + gbase + e] = rv;
    }
}

// ==== k_tabdec: blocks 0..128 = disc F table; block 129 = decoder scan ====
__global__ __launch_bounds__(256)
void k_tabdec(P29 a, float* __restrict__ ws)
{
    __shared__ __align__(16) float wl[PN];
    int tid = threadIdx.x;
    if (blockIdx.x < 129) {
#define STAGE(WS, BSi, h, K, padK, wdst, bdst) \
    { const float* Wp = a.p[WS]; const float* Bp2 = a.p[BSi]; \
      for (int i = tid; i < 3*(h)*(K); i += 256){ \
        int r = i/(K), k = i - r*(K); int g = r/(h), u0 = r - g*(h); \
        int sr = (g==0? u0 : (g==1? 2*(h)+u0 : 3*(h)+u0)); \
        wl[(wdst) + r*(padK) + k] = Wp[sr*(K) + k]; } \
      for (int i = tid; i < 3*(h); i += 256){ \
        int g = i/(h), u0 = i - g*(h); \
        int sr = (g==0? u0 : (g==1? 2*(h)+u0 : 3*(h)+u0)); \
        wl[(bdst) + i] = Bp2[sr]; } }
        STAGE(19, 20, 32,  1,  1, PW0, PB0)
        STAGE(21, 22, 16, 32, 36, PW1, PB1)
        STAGE(23, 24,  8, 16, 20, PW2, PB2)
        STAGE(25, 26, 16,  8, 12, PW3, PB3)
        STAGE(27, 28, 32, 16, 20, PW4, PB4)
#undef STAGE
        { const float* s = a.p[17]; for (int i = tid; i < 32; i += 256) wl[POW+i] = s[i]; }
        if (tid == 0) wl[POB] = a.p[18][0];
        __syncthreads();
        int u = tid & 15;
        int gbase = (tid & 63) & 48;
        int gid = blockIdx.x * 16 + (tid >> 4);
        const float4* w4 = (const float4*)wl;
        float xin = -8.f + (float)gid * (1.f/128.f);
        float lo = dunit(xin*wl[PW0+u]    + wl[PB0+u],
                         xin*wl[PW0+32+u] + wl[PB0+32+u],
                         xin*wl[PW0+64+u] + wl[PB0+64+u]);
        float hi = dunit(xin*wl[PW0+16+u] + wl[PB0+16+u],
                         xin*wl[PW0+48+u] + wl[PB0+48+u],
                         xin*wl[PW0+80+u] + wl[PB0+80+u]);
        float A0[32];
        #pragma unroll
        for (int k = 0; k < 16; k++) { A0[k] = __shfl(lo, gbase+k); A0[16+k] = __shfl(hi, gbase+k); }
        float gi = wl[PB1+u], gg = wl[PB1+16+u], go = wl[PB1+32+u];
        int bi_ = (PW1 + u*36)>>2, bg_ = (PW1 + (16+u)*36)>>2, bo_ = (PW1 + (32+u)*36)>>2;
        #pragma unroll
        for (int q = 0; q < 8; q++) {
            float4 wi = w4[bi_+q], wg = w4[bg_+q], wo = w4[bo_+q];
            float b0=A0[4*q], b1=A0[4*q+1], b2=A0[4*q+2], b3=A0[4*q+3];
            gi += b0*wi.x + b1*wi.y + b2*wi.z + b3*wi.w;
            gg += b0*wg.x + b1*wg.y + b2*wg.z + b3*wg.w;
            go += b0*wo.x + b1*wo.y + b2*wo.z + b3*wo.w;
        }
        float a1 = dunit(gi, gg, go);
        float A1[16];
        #pragma unroll
        for (int k = 0; k < 16; k++) A1[k] = __shfl(a1, gbase+k);
        int v = u & 7;
        gi = wl[PB2+v]; gg = wl[PB2+8+v]; go = wl[PB2+16+v];
        bi_ = (PW2 + v*20)>>2; bg_ = (PW2 + (8+v)*20)>>2; bo_ = (PW2 + (16+v)*20)>>2;
        #pragma unroll
        for (int q = 0; q < 4; q++) {
            float4 wi = w4[bi_+q], wg = w4[bg_+q], wo = w4[bo_+q];
            float b0=A1[4*q], b1=A1[4*q+1], b2=A1[4*q+2], b3=A1[4*q+3];
            gi += b0*wi.x + b1*wi.y + b2*wi.z + b3*wi.w;
            gg += b0*wg.x + b1*wg.y + b2*wg.z + b3*wg.w;
            go += b0*wo.x + b1*wo.y + b2*wo.z + b3*wo.w;
        }
        float a2 = dunit(gi, gg, go);
        float A2[8];
        #pragma unroll
        for (int k = 0; k < 8; k++) A2[k] = __shfl(a2, gbase+k);
        gi = wl[PB3+u]; gg = wl[PB3+16+u]; go = wl[PB3+32+u];
        bi_ = (PW3 + u*12)>>2; bg_ = (PW3 + (16+u)*12)>>2; bo_ = (PW3 + (32+u)*12)>>2;
        #pragma unroll
        for (int q = 0; q < 2; q++) {
            float4 wi = w4[bi_+q], wg = w4[bg_+q], wo = w4[bo_+q];
            float b0=A2[4*q], b1=A2[4*q+1], b2=A2[4*q+2], b3=A2[4*q+3];
            gi += b0*wi.x + b1*wi.y + b2*wi.z + b3*wi.w;
            gg += b0*wg.x + b1*wg.y + b2*wg.z + b3*wg.w;
            go += b0*wo.x + b1*wo.y + b2*wo.z + b3*wo.w;
        }
        float a3 = dunit(gi, gg, go);
        float A3[16];
        #pragma unroll
        for (int k = 0; k < 16; k++) A3[k] = __shfl(a3, gbase+k);
        float part;
        {
            float g0i = wl[PB4+u], g0g = wl[PB4+32+u], g0o = wl[PB4+64+u];
            float g1i = wl[PB4+16+u], g1g = wl[PB4+48+u], g1o = wl[PB4+80+u];
            int c0i = (PW4 + u*20)>>2,      c0g = (PW4 + (32+u)*20)>>2, c0o = (PW4 + (64+u)*20)>>2;
            int c1i = (PW4 + (16+u)*20)>>2, c1g = (PW4 + (48+u)*20)>>2, c1o = (PW4 + (80+u)*20)>>2;
            #pragma unroll
            for (int q = 0; q < 4; q++) {
                float b0=A3[4*q], b1=A3[4*q+1], b2=A3[4*q+2], b3=A3[4*q+3];
                float4 wi = w4[c0i+q], wg = w4[c0g+q], wo = w4[c0o+q];
                g0i += b0*wi.x + b1*wi.y + b2*wi.z + b3*wi.w;
                g0g += b0*wg.x + b1*wg.y + b2*wg.z + b3*wg.w;
                g0o += b0*wo.x + b1*wo.y + b2*wo.z + b3*wo.w;
                wi = w4[c1i+q]; wg = w4[c1g+q]; wo = w4[c1o+q];
                g1i += b0*wi.x + b1*wi.y + b2*wi.z + b3*wi.w;
                g1g += b0*wg.x + b1*wg.y + b2*wg.z + b3*wg.w;
                g1o += b0*wo.x + b1*wo.y + b2*wo.z + b3*wo.w;
            }
            part = dunit(g0i, g0g, g0o)*wl[POW+u] + dunit(g1i, g1g, g1o)*wl[POW+16+u];
        }
        part += __shfl_xor(part, 1);
        part += __shfl_xor(part, 2);
        part += __shfl_xor(part, 4);
        part += __shfl_xor(part, 8);
        if (u == 0 && gid < NTAB) ws[TAB + gid] = part + wl[POB];
        return;
    }
    // ---------------- decoder block ----------------
    {
        float* dh = wl;
        float* dc = wl + 16;
        const float* Wih = a.p[12];
        const float* Whh = a.p[13];
        const float* bb  = a.p[14];
        const float* oW  = a.p[15];
        const float* ob  = a.p[16];
        float wii[16], wff[16], wgg[16], woo[16];
        float vii[16], vff[16], vgg[16], voo[16];
        float bi_r=0, bf_r=0, bg_r=0, bo_r=0;
        if (tid < 16) {
            int uu = tid;
            #pragma unroll
            for (int k = 0; k < 16; k++) {
                wii[k]=Wih[uu*16+k];      vii[k]=Whh[uu*16+k];
                wff[k]=Wih[(16+uu)*16+k]; vff[k]=Whh[(16+uu)*16+k];
                wgg[k]=Wih[(32+uu)*16+k]; vgg[k]=Whh[(32+uu)*16+k];
                woo[k]=Wih[(48+uu)*16+k]; voo[k]=Whh[(48+uu)*16+k];
            }
            bi_r=bb[uu]; bf_r=bb[16+uu]; bg_r=bb[32+uu]; bo_r=bb[48+uu];
            float gi = bi_r, gg = bg_r, go = bo_r;
            #pragma unroll
            for (int k = 0; k < 16; k++) {
                gi += 128.f * wii[k];
                gg += 128.f * wgg[k];
                go += 128.f * woo[k];
            }
            float cd0 = sigm(gi) * tanh_f(gg);
            dc[tid] = cd0; dh[tid] = sigm(go) * tanh_f(cd0);
        }
        __syncthreads();
        for (int t = 0; t < 16; t++) {
            float rx[16], rh[16], cold = 0.f;
            if (tid < 16) {
                #pragma unroll
                for (int k = 0; k < 16; k++) { rx[k] = dc[k]; rh[k] = dh[k]; }
                cold = dc[tid];
            }
            __syncthreads();
            if (tid < 16) {
                float gi = bi_r, gf = bf_r, gg = bg_r, go = bo_r;
                #pragma unroll
                for (int k = 0; k < 16; k++) {
                    gi += rx[k]*wii[k] + rh[k]*vii[k];
                    gf += rx[k]*wff[k] + rh[k]*vff[k];
                    gg += rx[k]*wgg[k] + rh[k]*vgg[k];
                    go += rx[k]*woo[k] + rh[k]*voo[k];
                }
                float cn = sigm(gf)*cold + sigm(gi)*tanh_f(gg);
                dc[tid] = cn; dh[tid] = sigm(go)*tanh_f(cn);
            }
            __syncthreads();
            if (tid == 0) {
                float o = ob[0];
                #pragma unroll
                for (int k = 0; k < 16; k++) o += dh[k] * oW[k];
                ws[RECO + t] = o;
            }
            __syncthreads();
        }
    }
}

extern "C" void kernel_launch(void* const* d_in, const int* in_sizes, int n_in,
                              void* d_out, int out_size, void* d_ws, size_t ws_size,
                              hipStream_t stream)
{
    float* ws = (float*)d_ws;
    P29 a;
    for (int i = 0; i < 29; i++) a.p[i] = (const float*)d_in[i];
    const int* masks = (const int*)d_in[1];
    k_tabdec<<<130, 256, 0, stream>>>(a, ws);
    k_fused<<<1024, 256, 0, stream>>>(a, masks, ws, (float*)d_out);
}

// Round 15
// 163.646 us; speedup vs baseline: 1.1099x; 1.0007x over previous
//
#include <hip/hip_runtime.h>

#define BB 32768
#define BS (BB*16)   // 524288

typedef __attribute__((ext_vector_type(8))) short bf8v;   // 8 bf16 (4 VGPRs)
typedef __attribute__((ext_vector_type(4))) float f4v;

// ---- ws float offsets ----
#define RECO 64
#define TAB  128             // disc F table, 2049 floats over [-8,8], step 1/128
#define NTAB 2049
#define HFO  8448
#define HBO  (HFO+BS)

// ---- table-path LDS layout ----
#define PW0 0
#define PB0 96
#define PW1 192
#define PB1 1920
#define PW2 1968
#define PB2 2448
#define PW3 2472
#define PB3 3048
#define PW4 3096
#define PB4 5016
#define POW 5112
#define POB 5144
#define PN  5148

#define NSCAN 1024
#define NTABB 129
#define DECB  (NSCAN + NTABB)    // 1153

__device__ __forceinline__ float sigm(float x){
    return __builtin_amdgcn_rcpf(1.f + __expf(-x));
}
__device__ __forceinline__ float tanh_f(float x){
    return 1.f - 2.f * __builtin_amdgcn_rcpf(1.f + __expf(2.f * x));
}
__device__ __forceinline__ float dunit(float gi, float gg, float go){
    return sigm(go) * tanh_f(sigm(gi) * tanh_f(gg));
}
__device__ __forceinline__ unsigned short f2bf(float f){   // RNE
    union { float f; unsigned int i; } v; v.f = f;
    unsigned int x = v.i;
    unsigned int r = x + 0x7fffu + ((x >> 16) & 1u);
    return (unsigned short)(r >> 16);
}

struct P29 { const float* p[29]; };
// 0 values 1 masks 2-4 g_fwd(Wih,Whh,b) 5-7 g_bwd 8 impW 9 impb
// 10 fcW 11 fcb 12-14 dec(Wih,Whh,b) 15 dec_out_W 16 dec_out_b 17 disc_out_W
// 18 disc_out_b 19/20 d_W_0/d_b_0 ... 27/28 d_W_4/d_b_4

// B fragment: B[k=quad*8+j][n]; k<16 = Whh row, k=16 = Wih (cc), else 0.
// Layout HW-validated (r13: absmax 1.95e-3).
__device__ __forceinline__ bf8v makeB(const float* Whh, const float* Wih,
                                      int row, int quad)
{
    bf8v B = {0,0,0,0,0,0,0,0};
    if (quad < 2) {
        const float4* p = (const float4*)(Whh + row*16 + quad*8);
        float4 a0 = p[0], a1 = p[1];
        B[0]=(short)f2bf(a0.x); B[1]=(short)f2bf(a0.y);
        B[2]=(short)f2bf(a0.z); B[3]=(short)f2bf(a0.w);
        B[4]=(short)f2bf(a1.x); B[5]=(short)f2bf(a1.y);
        B[6]=(short)f2bf(a1.z); B[7]=(short)f2bf(a1.w);
    } else if (quad == 2) {
        B[0] = (short)f2bf(Wih[row]);
    }
    return B;
}

// ==== k_main: blocks 0..1023 = MFMA scan (r13 proven form: wave = 16 groups,
//      single dir, 5 B-fragments = 20 VGPRs — the only form the allocator
//      keeps resident); blocks 1024..1152 = disc F table; 1153 = decoder.
//      Table work now overlaps the scan instead of serializing (~10-15us). ====
__global__ __launch_bounds__(256)
void k_main(P29 a, const int* __restrict__ masks, float* __restrict__ ws)
{
    __shared__ __align__(16) float smem[PN];     // scan uses first 2624
    int tid = threadIdx.x;

    if (blockIdx.x < NSCAN) {
        // ---------------- scan path ----------------
        int lane = tid & 63;
        int wv   = tid >> 6;
        int n    = lane & 15;
        int quad = lane >> 4;
        int dir  = (int)(blockIdx.x >= 512);
        int gid0 = blockIdx.x * 64 + wv * 16;
        int b0   = gid0 & 32767;
        float* wbase = smem + wv * 656;
        float* xs    = wbase;                        // [t][m] 256
        int*   msI   = (int*)(wbase + 256);          // [t][m] 256
        unsigned short* hbp = (unsigned short*)(wbase + 512);  // h bf16 [m][u]
        float* ccf   = wbase + 640;                  // cc[m] 16
        const int4* hbI = (const int4*)hbp;
        {
            size_t gbase = (size_t)b0 * 16;
            int e = lane * 4;
            float4 xv = *(const float4*)(a.p[0] + gbase + e);
            int4   mv = *(const int4*)(masks + gbase + e);
            int sm = lane >> 2;
            int st = (lane & 3) * 4;
            xs[(st+0)*16 + sm] = xv.x;  msI[(st+0)*16 + sm] = mv.x;
            xs[(st+1)*16 + sm] = xv.y;  msI[(st+1)*16 + sm] = mv.y;
            xs[(st+2)*16 + sm] = xv.z;  msI[(st+2)*16 + sm] = mv.z;
            xs[(st+3)*16 + sm] = xv.w;  msI[(st+3)*16 + sm] = mv.w;
        }
        const float* __restrict__ Wih = a.p[2 + 3*dir];
        const float* __restrict__ Whh = a.p[3 + 3*dir];
        const float* __restrict__ bia = a.p[4 + 3*dir];
        bf8v Bi = makeB(Whh, Wih, n,      quad);
        bf8v Bf = makeB(Whh, Wih, 16+n,   quad);
        bf8v Bg = makeB(Whh, Wih, 32+n,   quad);
        bf8v Bo = makeB(Whh, Wih, 48+n,   quad);
        bf8v Bp = {0,0,0,0,0,0,0,0};
        if (quad < 2) {
            const float4* p = (const float4*)(a.p[8] + quad*8);
            float4 a0 = p[0], a1 = p[1];
            Bp[0]=(short)f2bf(a0.x); Bp[1]=(short)f2bf(a0.y);
            Bp[2]=(short)f2bf(a0.z); Bp[3]=(short)f2bf(a0.w);
            Bp[4]=(short)f2bf(a1.x); Bp[5]=(short)f2bf(a1.y);
            Bp[6]=(short)f2bf(a1.z); Bp[7]=(short)f2bf(a1.w);
        }
        float impb = a.p[9][0];
        float bi_ = bia[n], bf_ = bia[16+n], bg_ = bia[32+n], bo_ = bia[48+n];
        float sgn = dir ? -128.f : 128.f;
        float c0, h0;
        {
            float gi0 = sgn*Wih[n]    + bi_;
            float gg0 = sgn*Wih[32+n] + bg_;
            float go0 = sgn*Wih[48+n] + bo_;
            c0 = sigm(gi0) * tanh_f(gg0);
            h0 = sigm(go0) * tanh_f(c0);
        }
        float c[4] = {c0, c0, c0, c0};
        float h[4];
        {
            unsigned short hb0 = f2bf(h0);
            #pragma unroll
            for (int r = 0; r < 4; r++) hbp[(quad*4+r)*16 + n] = hb0;
        }
        const f4v cz = {0.f, 0.f, 0.f, 0.f};
        const bf8v Az = {0,0,0,0,0,0,0,0};
        for (int t = 0; t < 16; t++) {
            union { int4 i4; bf8v b; } au;
            au.i4 = hbI[(n << 1) | (quad & 1)];
            bf8v A = (quad < 2) ? au.b : Az;
            f4v dimp = __builtin_amdgcn_mfma_f32_16x16x32_bf16(A, Bp, cz, 0, 0, 0);
            float4 xt4 = *(const float4*)(xs + t*16 + quad*4);
            int4   mt4 = *(const int4*)(msI + t*16 + quad*4);
            float cc0 = mt4.x ? (dimp[0] + impb) : xt4.x;
            float cc1 = mt4.y ? (dimp[1] + impb) : xt4.y;
            float cc2 = mt4.z ? (dimp[2] + impb) : xt4.z;
            float cc3 = mt4.w ? (dimp[3] + impb) : xt4.w;
            if (n == 0) {
                ccf[quad*4+0] = cc0; ccf[quad*4+1] = cc1;
                ccf[quad*4+2] = cc2; ccf[quad*4+3] = cc3;
            }
            if (quad == 2) A[0] = (short)f2bf(ccf[n]);   // cc at k=16
            f4v di = __builtin_amdgcn_mfma_f32_16x16x32_bf16(A, Bi, cz, 0, 0, 0);
            f4v df = __builtin_amdgcn_mfma_f32_16x16x32_bf16(A, Bf, cz, 0, 0, 0);
            f4v dg = __builtin_amdgcn_mfma_f32_16x16x32_bf16(A, Bg, cz, 0, 0, 0);
            f4v dO = __builtin_amdgcn_mfma_f32_16x16x32_bf16(A, Bo, cz, 0, 0, 0);
            #pragma unroll
            for (int r = 0; r < 4; r++) {
                float gi = di[r] + bi_;
                float gf = df[r] + bf_;
                float gg = dg[r] + bg_;
                float go = dO[r] + bo_;
                float cn = sigm(gf)*c[r] + sigm(gi)*tanh_f(gg);
                c[r] = cn;
                float hh = sigm(go)*tanh_f(cn);
                h[r] = hh;
                hbp[(quad*4+r)*16 + n] = f2bf(hh);
            }
        }
        float* outp = ws + HFO + (size_t)dir*BS + (size_t)b0*16;
        #pragma unroll
        for (int r = 0; r < 4; r++) outp[(quad*4+r)*16 + n] = h[r];
        return;
    }

    if (blockIdx.x < DECB) {
        // ---------------- F-table path: 16 lanes per entry ----------------
        float* wl = smem;
#define STAGE(WS, BSi, h, K, padK, wdst, bdst) \
    { const float* Wp = a.p[WS]; const float* Bp2 = a.p[BSi]; \
      for (int i = tid; i < 3*(h)*(K); i += 256){ \
        int r = i/(K), k = i - r*(K); int g = r/(h), u0 = r - g*(h); \
        int sr = (g==0? u0 : (g==1? 2*(h)+u0 : 3*(h)+u0)); \
        wl[(wdst) + r*(padK) + k] = Wp[sr*(K) + k]; } \
      for (int i = tid; i < 3*(h); i += 256){ \
        int g = i/(h), u0 = i - g*(h); \
        int sr = (g==0? u0 : (g==1? 2*(h)+u0 : 3*(h)+u0)); \
        wl[(bdst) + i] = Bp2[sr]; } }
        STAGE(19, 20, 32,  1,  1, PW0, PB0)
        STAGE(21, 22, 16, 32, 36, PW1, PB1)
        STAGE(23, 24,  8, 16, 20, PW2, PB2)
        STAGE(25, 26, 16,  8, 12, PW3, PB3)
        STAGE(27, 28, 32, 16, 20, PW4, PB4)
#undef STAGE
        { const float* s = a.p[17]; for (int i = tid; i < 32; i += 256) wl[POW+i] = s[i]; }
        if (tid == 0) wl[POB] = a.p[18][0];
        __syncthreads();
        int u = tid & 15;
        int gbase = (tid & 63) & 48;
        int gid = (blockIdx.x - NSCAN) * 16 + (tid >> 4);
        const float4* w4 = (const float4*)wl;
        float xin = -8.f + (float)gid * (1.f/128.f);
        float lo = dunit(xin*wl[PW0+u]    + wl[PB0+u],
                         xin*wl[PW0+32+u] + wl[PB0+32+u],
                         xin*wl[PW0+64+u] + wl[PB0+64+u]);
        float hi = dunit(xin*wl[PW0+16+u] + wl[PB0+16+u],
                         xin*wl[PW0+48+u] + wl[PB0+48+u],
                         xin*wl[PW0+80+u] + wl[PB0+80+u]);
        float A0[32];
        #pragma unroll
        for (int k = 0; k < 16; k++) { A0[k] = __shfl(lo, gbase+k); A0[16+k] = __shfl(hi, gbase+k); }
        float gi = wl[PB1+u], gg = wl[PB1+16+u], go = wl[PB1+32+u];
        int bi_ = (PW1 + u*36)>>2, bg_ = (PW1 + (16+u)*36)>>2, bo_ = (PW1 + (32+u)*36)>>2;
        #pragma unroll
        for (int q = 0; q < 8; q++) {
            float4 wi = w4[bi_+q], wg = w4[bg_+q], wo = w4[bo_+q];
            float b0=A0[4*q], b1=A0[4*q+1], b2=A0[4*q+2], b3=A0[4*q+3];
            gi += b0*wi.x + b1*wi.y + b2*wi.z + b3*wi.w;
            gg += b0*wg.x + b1*wg.y + b2*wg.z + b3*wg.w;
            go += b0*wo.x + b1*wo.y + b2*wo.z + b3*wo.w;
        }
        float a1 = dunit(gi, gg, go);
        float A1[16];
        #pragma unroll
        for (int k = 0; k < 16; k++) A1[k] = __shfl(a1, gbase+k);
        int v = u & 7;
        gi = wl[PB2+v]; gg = wl[PB2+8+v]; go = wl[PB2+16+v];
        bi_ = (PW2 + v*20)>>2; bg_ = (PW2 + (8+v)*20)>>2; bo_ = (PW2 + (16+v)*20)>>2;
        #pragma unroll
        for (int q = 0; q < 4; q++) {
            float4 wi = w4[bi_+q], wg = w4[bg_+q], wo = w4[bo_+q];
            float b0=A1[4*q], b1=A1[4*q+1], b2=A1[4*q+2], b3=A1[4*q+3];
            gi += b0*wi.x + b1*wi.y + b2*wi.z + b3*wi.w;
            gg += b0*wg.x + b1*wg.y + b2*wg.z + b3*wg.w;
            go += b0*wo.x + b1*wo.y + b2*wo.z + b3*wo.w;
        }
        float a2 = dunit(gi, gg, go);
        float A2[8];
        #pragma unroll
        for (int k = 0; k < 8; k++) A2[k] = __shfl(a2, gbase+k);
        gi = wl[PB3+u]; gg = wl[PB3+16+u]; go = wl[PB3+32+u];
        bi_ = (PW3 + u*12)>>2; bg_ = (PW3 + (16+u)*12)>>2; bo_ = (PW3 + (32+u)*12)>>2;
        #pragma unroll
        for (int q = 0; q < 2; q++) {
            float4 wi = w4[bi_+q], wg = w4[bg_+q], wo = w4[bo_+q];
            float b0=A2[4*q], b1=A2[4*q+1], b2=A2[4*q+2], b3=A2[4*q+3];
            gi += b0*wi.x + b1*wi.y + b2*wi.z + b3*wi.w;
            gg += b0*wg.x + b1*wg.y + b2*wg.z + b3*wg.w;
            go += b0*wo.x + b1*wo.y + b2*wo.z + b3*wo.w;
        }
        float a3 = dunit(gi, gg, go);
        float A3[16];
        #pragma unroll
        for (int k = 0; k < 16; k++) A3[k] = __shfl(a3, gbase+k);
        float part;
        {
            float g0i = wl[PB4+u], g0g = wl[PB4+32+u], g0o = wl[PB4+64+u];
            float g1i = wl[PB4+16+u], g1g = wl[PB4+48+u], g1o = wl[PB4+80+u];
            int c0i = (PW4 + u*20)>>2,      c0g = (PW4 + (32+u)*20)>>2, c0o = (PW4 + (64+u)*20)>>2;
            int c1i = (PW4 + (16+u)*20)>>2, c1g = (PW4 + (48+u)*20)>>2, c1o = (PW4 + (80+u)*20)>>2;
            #pragma unroll
            for (int q = 0; q < 4; q++) {
                float b0=A3[4*q], b1=A3[4*q+1], b2=A3[4*q+2], b3=A3[4*q+3];
                float4 wi = w4[c0i+q], wg = w4[c0g+q], wo = w4[c0o+q];
                g0i += b0*wi.x + b1*wi.y + b2*wi.z + b3*wi.w;
                g0g += b0*wg.x + b1*wg.y + b2*wg.z + b3*wg.w;
                g0o += b0*wo.x + b1*wo.y + b2*wo.z + b3*wo.w;
                wi = w4[c1i+q]; wg = w4[c1g+q]; wo = w4[c1o+q];
                g1i += b0*wi.x + b1*wi.y + b2*wi.z + b3*wi.w;
                g1g += b0*wg.x + b1*wg.y + b2*wg.z + b3*wg.w;
                g1o += b0*wo.x + b1*wo.y + b2*wo.z + b3*wo.w;
            }
            part = dunit(g0i, g0g, g0o)*wl[POW+u] + dunit(g1i, g1g, g1o)*wl[POW+16+u];
        }
        part += __shfl_xor(part, 1);
        part += __shfl_xor(part, 2);
        part += __shfl_xor(part, 4);
        part += __shfl_xor(part, 8);
        if (u == 0 && gid < NTAB) ws[TAB + gid] = part + wl[POB];
        return;
    }

    // ---------------- decoder block (batch-invariant scan) ----------------
    {
        float* dh = smem;
        float* dc = smem + 16;
        const float* Wih = a.p[12];
        const float* Whh = a.p[13];
        const float* bb  = a.p[14];
        const float* oW  = a.p[15];
        const float* ob  = a.p[16];
        float wii[16], wff[16], wgg[16], woo[16];
        float vii[16], vff[16], vgg[16], voo[16];
        float bi_r=0, bf_r=0, bg_r=0, bo_r=0;
        if (tid < 16) {
            int uu = tid;
            #pragma unroll
            for (int k = 0; k < 16; k++) {
                wii[k]=Wih[uu*16+k];      vii[k]=Whh[uu*16+k];
                wff[k]=Wih[(16+uu)*16+k]; vff[k]=Whh[(16+uu)*16+k];
                wgg[k]=Wih[(32+uu)*16+k]; vgg[k]=Whh[(32+uu)*16+k];
                woo[k]=Wih[(48+uu)*16+k]; voo[k]=Whh[(48+uu)*16+k];
            }
            bi_r=bb[uu]; bf_r=bb[16+uu]; bg_r=bb[32+uu]; bo_r=bb[48+uu];
            float gi = bi_r, gg = bg_r, go = bo_r;
            #pragma unroll
            for (int k = 0; k < 16; k++) {
                gi += 128.f * wii[k];
                gg += 128.f * wgg[k];
                go += 128.f * woo[k];
            }
            float cd0 = sigm(gi) * tanh_f(gg);
            dc[tid] = cd0; dh[tid] = sigm(go) * tanh_f(cd0);
        }
        __syncthreads();
        for (int t = 0; t < 16; t++) {
            float rx[16], rh[16], cold = 0.f;
            if (tid < 16) {
                #pragma unroll
                for (int k = 0; k < 16; k++) { rx[k] = dc[k]; rh[k] = dh[k]; }
                cold = dc[tid];
            }
            __syncthreads();
            if (tid < 16) {
                float gi = bi_r, gf = bf_r, gg = bg_r, go = bo_r;
                #pragma unroll
                for (int k = 0; k < 16; k++) {
                    gi += rx[k]*wii[k] + rh[k]*vii[k];
                    gf += rx[k]*wff[k] + rh[k]*vff[k];
                    gg += rx[k]*wgg[k] + rh[k]*vgg[k];
                    go += rx[k]*woo[k] + rh[k]*voo[k];
                }
                float cn = sigm(gf)*cold + sigm(gi)*tanh_f(gg);
                dc[tid] = cn; dh[tid] = sigm(go)*tanh_f(cn);
            }
            __syncthreads();
            if (tid == 0) {
                float o = ob[0];
                #pragma unroll
                for (int k = 0; k < 16; k++) o += dh[k] * oW[k];
                ws[RECO + t] = o;
            }
            __syncthreads();
        }
    }
}

// ---- k_post: 4 elements per thread; fcW/rec/table staged in LDS ----
__global__ __launch_bounds__(256) void k_post(P29 a, const int* __restrict__ masks,
                                              const float* __restrict__ ws,
                                              float* __restrict__ out)
{
    __shared__ float tab[NTAB];
    __shared__ __align__(16) float fw[256];
    __shared__ __align__(16) float rec[16];
    __shared__ float fb[16];
    int tid = threadIdx.x;
    for (int i = tid; i < NTAB; i += 256) tab[i] = ws[TAB + i];
    fw[tid] = a.p[10][tid];
    if (tid < 16) { fb[tid] = a.p[11][tid]; rec[tid] = ws[RECO + tid]; }
    __syncthreads();
    int T = blockIdx.x * 256 + tid;
    int b = T >> 2;
    int q = T & 3;
    int tq = q * 4;
    const float4* hf4 = (const float4*)(ws + HFO + (size_t)b*16);
    const float4* hb4 = (const float4*)(ws + HBO + (size_t)b*16);
    float4 s0, s1, s2, s3;
    {
        float4 f0=hf4[0], f1=hf4[1], f2=hf4[2], f3=hf4[3];
        float4 g0=hb4[0], g1=hb4[1], g2=hb4[2], g3=hb4[3];
        s0 = make_float4(f0.x+g0.x, f0.y+g0.y, f0.z+g0.z, f0.w+g0.w);
        s1 = make_float4(f1.x+g1.x, f1.y+g1.y, f1.z+g1.z, f1.w+g1.w);
        s2 = make_float4(f2.x+g2.x, f2.y+g2.y, f2.z+g2.z, f2.w+g2.w);
        s3 = make_float4(f3.x+g3.x, f3.y+g3.y, f3.z+g3.z, f3.w+g3.w);
    }
    float4 hq = (q==0) ? s0 : (q==1) ? s1 : (q==2) ? s2 : s3;
    float4 xv = *(const float4*)(a.p[0] + (size_t)b*16 + tq);
    int4   mv = *(const int4*)(masks + (size_t)b*16 + tq);
    float impv[4];
    impv[0] = mv.x ? xv.x : hq.x;
    impv[1] = mv.y ? xv.y : hq.y;
    impv[2] = mv.z ? xv.z : hq.z;
    impv[3] = mv.w ? xv.w : hq.w;
    float latv[4];
    #pragma unroll
    for (int j = 0; j < 4; j++) {
        int t = tq + j;
        const float4* wr = (const float4*)(fw + t*16);
        float4 w0=wr[0], w1=wr[1], w2=wr[2], w3=wr[3];
        float l = fb[t];
        l += s0.x*w0.x + s0.y*w0.y + s0.z*w0.z + s0.w*w0.w;
        l += s1.x*w1.x + s1.y*w1.y + s1.z*w1.z + s1.w*w1.w;
        l += s2.x*w2.x + s2.y*w2.y + s2.z*w2.z + s2.w*w2.w;
        l += s3.x*w3.x + s3.y*w3.y + s3.z*w3.z + s3.w*w3.w;
        latv[j] = l;
    }
    float dv[4];
    #pragma unroll
    for (int j = 0; j < 4; j++) {
        float xx = fminf(fmaxf(impv[j], -8.f), 8.f);
        float f = (xx + 8.f) * 128.f;
        float fi = floorf(f);
        int i = (int)fi; i = i > NTAB-2 ? NTAB-2 : i;
        float w = f - fi;
        dv[j] = fmaf(w, tab[i+1] - tab[i], tab[i]);
    }
    float4 rv = ((const float4*)rec)[q];
    size_t eo = (size_t)b*16 + tq;
    *(float4*)(out + eo)        = make_float4(impv[0], impv[1], impv[2], impv[3]);
    *(float4*)(out + BS + eo)   = make_float4(dv[0], dv[1], dv[2], dv[3]);
    *(float4*)(out + 2*BS + eo) = make_float4(latv[0], latv[1], latv[2], latv[3]);
    *(float4*)(out + 3*BS + eo) = rv;
}

extern "C" void kernel_launch(void* const* d_in, const int* in_sizes, int n_in,
                              void* d_out, int out_size, void* d_ws, size_t ws_size,
                              hipStream_t stream)
{
    float* ws = (float*)d_ws;
    P29 a;
    for (int i = 0; i < 29; i++) a.p[i] = (const float*)d_in[i];
    const int* masks = (const int*)d_in[1];
    k_main<<<NSCAN + NTABB + 1, 256, 0, stream>>>(a, masks, ws);  // scan ∥ table ∥ decoder
    k_post<<<(BB*4)/256, 256, 0, stream>>>(a, masks, ws, (float*)d_out);
}

// Round 16
// 160.036 us; speedup vs baseline: 1.1350x; 1.0226x over previous
//
#include <hip/hip_runtime.h>

#define BB 32768
#define BS (BB*16)   // 524288

typedef __attribute__((ext_vector_type(8))) short bf8v;   // 8 bf16 (4 VGPRs)
typedef __attribute__((ext_vector_type(4))) float f4v;

// ---- ws float offsets ----
#define RECO 64
#define TAB  128             // disc F table, 2049 floats over [-8,8], step 1/128
#define NTAB 2049
#define HFO  8448
#define HBO  (HFO+BS)

// ---- table-path LDS layout (USHORT indices; weights stored bf16) ----
#define PW0 0
#define PB0 96
#define PW1 192    // 48 rows x 36
#define PB1 1920
#define PW2 1968   // 24 x 20
#define PB2 2448
#define PW3 2472   // 48 x 12
#define PB3 3048
#define PW4 3096   // 96 x 20
#define PB4 5016
#define POW 5112
#define POB 5144
#define PNU 5148             // ushorts = 10.3KB

// ---- scan per-wave LDS layout (float offsets within wbase) ----
// xs 16x20=320 | msI 320 | hb 16 rows x 24 ushorts = 192 floats | ccf 16
#define WVF 848              // floats per wave
#define SMF 3392             // 4 waves -> 13568 B (union holds table's 10.3KB)

#define NSCAN 1024
#define NTABB 129
#define DECB  (NSCAN + NTABB)    // 1153

__device__ __forceinline__ float sigm(float x){
    return __builtin_amdgcn_rcpf(1.f + __expf(-x));
}
__device__ __forceinline__ float tanh_f(float x){
    return 1.f - 2.f * __builtin_amdgcn_rcpf(1.f + __expf(2.f * x));
}
__device__ __forceinline__ float dunit(float gi, float gg, float go){
    return sigm(go) * tanh_f(sigm(gi) * tanh_f(gg));
}
__device__ __forceinline__ unsigned short f2bf(float f){   // RNE
    union { float f; unsigned int i; } v; v.f = f;
    unsigned int x = v.i;
    unsigned int r = x + 0x7fffu + ((x >> 16) & 1u);
    return (unsigned short)(r >> 16);
}
__device__ __forceinline__ float bfu(unsigned short s){
    union { unsigned u; float f; } v; v.u = ((unsigned)s) << 16; return v.f;
}
__device__ __forceinline__ float bflo(unsigned p){
    union { unsigned u; float f; } v; v.u = p << 16; return v.f;
}
__device__ __forceinline__ float bfhi(unsigned p){
    union { unsigned u; float f; } v; v.u = p & 0xffff0000u; return v.f;
}

struct P29 { const float* p[29]; };
// 0 values 1 masks 2-4 g_fwd(Wih,Whh,b) 5-7 g_bwd 8 impW 9 impb
// 10 fcW 11 fcb 12-14 dec(Wih,Whh,b) 15 dec_out_W 16 dec_out_b 17 disc_out_W
// 18 disc_out_b 19/20 d_W_0/d_b_0 ... 27/28 d_W_4/d_b_4

// B fragment: B[k=quad*8+j][n]; k<16 = Whh row, k=16 = Wih (cc), else 0.
// Layout HW-validated (r13: absmax 1.95e-3).
__device__ __forceinline__ bf8v makeB(const float* Whh, const float* Wih,
                                      int row, int quad)
{
    bf8v B = {0,0,0,0,0,0,0,0};
    if (quad < 2) {
        const float4* p = (const float4*)(Whh + row*16 + quad*8);
        float4 a0 = p[0], a1 = p[1];
        B[0]=(short)f2bf(a0.x); B[1]=(short)f2bf(a0.y);
        B[2]=(short)f2bf(a0.z); B[3]=(short)f2bf(a0.w);
        B[4]=(short)f2bf(a1.x); B[5]=(short)f2bf(a1.y);
        B[6]=(short)f2bf(a1.z); B[7]=(short)f2bf(a1.w);
    } else if (quad == 2) {
        B[0] = (short)f2bf(Wih[row]);
    }
    return B;
}

// ==== k_main: 0..1023 MFMA scan | 1024..1152 disc F table | 1153 decoder ====
__global__ __launch_bounds__(256)
void k_main(P29 a, const int* __restrict__ masks, float* __restrict__ ws)
{
    __shared__ __align__(16) float smem[SMF];
    int tid = threadIdx.x;

    if (blockIdx.x < NSCAN) {
        // ---------------- scan path ----------------
        int lane = tid & 63;
        int wv   = tid >> 6;
        int n    = lane & 15;
        int quad = lane >> 4;
        int dir  = (int)(blockIdx.x >= 512);
        int gid0 = blockIdx.x * 64 + wv * 16;
        int b0   = gid0 & 32767;
        float* wbase = smem + wv * WVF;
        float* xs    = wbase;                        // [t][m] pad 20
        int*   msI   = (int*)(wbase + 320);          // [t][m] pad 20
        unsigned short* hbp = (unsigned short*)(wbase + 640);  // [m] pad 24 ushorts
        float* ccf   = wbase + 832;                  // cc[m] 16
        const int4* hbI = (const int4*)hbp;
        {
            size_t gbase = (size_t)b0 * 16;
            int e = lane * 4;
            float4 xv = *(const float4*)(a.p[0] + gbase + e);
            int4   mv = *(const int4*)(masks + gbase + e);
            int sm = lane >> 2;
            int st = (lane & 3) * 4;
            xs[(st+0)*20 + sm] = xv.x;  msI[(st+0)*20 + sm] = mv.x;
            xs[(st+1)*20 + sm] = xv.y;  msI[(st+1)*20 + sm] = mv.y;
            xs[(st+2)*20 + sm] = xv.z;  msI[(st+2)*20 + sm] = mv.z;
            xs[(st+3)*20 + sm] = xv.w;  msI[(st+3)*20 + sm] = mv.w;
        }
        const float* __restrict__ Wih = a.p[2 + 3*dir];
        const float* __restrict__ Whh = a.p[3 + 3*dir];
        const float* __restrict__ bia = a.p[4 + 3*dir];
        bf8v Bi = makeB(Whh, Wih, n,      quad);
        bf8v Bf = makeB(Whh, Wih, 16+n,   quad);
        bf8v Bg = makeB(Whh, Wih, 32+n,   quad);
        bf8v Bo = makeB(Whh, Wih, 48+n,   quad);
        bf8v Bp = {0,0,0,0,0,0,0,0};
        if (quad < 2) {
            const float4* p = (const float4*)(a.p[8] + quad*8);
            float4 a0 = p[0], a1 = p[1];
            Bp[0]=(short)f2bf(a0.x); Bp[1]=(short)f2bf(a0.y);
            Bp[2]=(short)f2bf(a0.z); Bp[3]=(short)f2bf(a0.w);
            Bp[4]=(short)f2bf(a1.x); Bp[5]=(short)f2bf(a1.y);
            Bp[6]=(short)f2bf(a1.z); Bp[7]=(short)f2bf(a1.w);
        }
        float impb = a.p[9][0];
        float bi_ = bia[n], bf_ = bia[16+n], bg_ = bia[32+n], bo_ = bia[48+n];
        float sgn = dir ? -128.f : 128.f;
        float c0, h0;
        {
            float gi0 = sgn*Wih[n]    + bi_;
            float gg0 = sgn*Wih[32+n] + bg_;
            float go0 = sgn*Wih[48+n] + bo_;
            c0 = sigm(gi0) * tanh_f(gg0);
            h0 = sigm(go0) * tanh_f(c0);
        }
        float c[4] = {c0, c0, c0, c0};
        float h[4];
        {
            unsigned short hb0 = f2bf(h0);
            #pragma unroll
            for (int r = 0; r < 4; r++) hbp[(quad*4+r)*24 + n] = hb0;
        }
        const f4v cz = {0.f, 0.f, 0.f, 0.f};
        const bf8v Az = {0,0,0,0,0,0,0,0};
        for (int t = 0; t < 16; t++) {
            union { int4 i4; bf8v b; } au;
            au.i4 = hbI[n*3 + (quad & 1)];
            bf8v A = (quad < 2) ? au.b : Az;
            f4v dimp = __builtin_amdgcn_mfma_f32_16x16x32_bf16(A, Bp, cz, 0, 0, 0);
            float4 xt4 = *(const float4*)(xs + t*20 + quad*4);
            int4   mt4 = *(const int4*)(msI + t*20 + quad*4);
            float cc0 = mt4.x ? (dimp[0] + impb) : xt4.x;
            float cc1 = mt4.y ? (dimp[1] + impb) : xt4.y;
            float cc2 = mt4.z ? (dimp[2] + impb) : xt4.z;
            float cc3 = mt4.w ? (dimp[3] + impb) : xt4.w;
            if (n == 0) {
                ccf[quad*4+0] = cc0; ccf[quad*4+1] = cc1;
                ccf[quad*4+2] = cc2; ccf[quad*4+3] = cc3;
            }
            if (quad == 2) A[0] = (short)f2bf(ccf[n]);   // cc at k=16
            f4v di = __builtin_amdgcn_mfma_f32_16x16x32_bf16(A, Bi, cz, 0, 0, 0);
            f4v df = __builtin_amdgcn_mfma_f32_16x16x32_bf16(A, Bf, cz, 0, 0, 0);
            f4v dg = __builtin_amdgcn_mfma_f32_16x16x32_bf16(A, Bg, cz, 0, 0, 0);
            f4v dO = __builtin_amdgcn_mfma_f32_16x16x32_bf16(A, Bo, cz, 0, 0, 0);
            #pragma unroll
            for (int r = 0; r < 4; r++) {
                float gi = di[r] + bi_;
                float gf = df[r] + bf_;
                float gg = dg[r] + bg_;
                float go = dO[r] + bo_;
                float cn = sigm(gf)*c[r] + sigm(gi)*tanh_f(gg);
                c[r] = cn;
                float hh = sigm(go)*tanh_f(cn);
                h[r] = hh;
                hbp[(quad*4+r)*24 + n] = f2bf(hh);
            }
        }
        float* outp = ws + HFO + (size_t)dir*BS + (size_t)b0*16;
        #pragma unroll
        for (int r = 0; r < 4; r++) outp[(quad*4+r)*16 + n] = h[r];
        return;
    }

    if (blockIdx.x < DECB) {
        // -------- F-table path: bf16 weights in LDS (10.3KB), 16 lanes/entry --------
        unsigned short* wl = (unsigned short*)smem;
#define STAGE(WS, BSi, h, K, padK, wdst, bdst) \
    { const float* Wp = a.p[WS]; const float* Bp2 = a.p[BSi]; \
      for (int i = tid; i < 3*(h)*(K); i += 256){ \
        int r = i/(K), k = i - r*(K); int g = r/(h), u0 = r - g*(h); \
        int sr = (g==0? u0 : (g==1? 2*(h)+u0 : 3*(h)+u0)); \
        wl[(wdst) + r*(padK) + k] = f2bf(Wp[sr*(K) + k]); } \
      for (int i = tid; i < 3*(h); i += 256){ \
        int g = i/(h), u0 = i - g*(h); \
        int sr = (g==0? u0 : (g==1? 2*(h)+u0 : 3*(h)+u0)); \
        wl[(bdst) + i] = f2bf(Bp2[sr]); } }
        STAGE(19, 20, 32,  1,  1, PW0, PB0)
        STAGE(21, 22, 16, 32, 36, PW1, PB1)
        STAGE(23, 24,  8, 16, 20, PW2, PB2)
        STAGE(25, 26, 16,  8, 12, PW3, PB3)
        STAGE(27, 28, 32, 16, 20, PW4, PB4)
#undef STAGE
        { const float* s = a.p[17]; for (int i = tid; i < 32; i += 256) wl[POW+i] = f2bf(s[i]); }
        if (tid == 0) wl[POB] = f2bf(a.p[18][0]);
        __syncthreads();
        int u = tid & 15;
        int gbase = (tid & 63) & 48;
        int gid = (blockIdx.x - NSCAN) * 16 + (tid >> 4);
        const uint2* w2 = (const uint2*)wl;      // index = ushort_idx/4
        float xin = -8.f + (float)gid * (1.f/128.f);
        float lo = dunit(xin*bfu(wl[PW0+u])    + bfu(wl[PB0+u]),
                         xin*bfu(wl[PW0+32+u]) + bfu(wl[PB0+32+u]),
                         xin*bfu(wl[PW0+64+u]) + bfu(wl[PB0+64+u]));
        float hi = dunit(xin*bfu(wl[PW0+16+u]) + bfu(wl[PB0+16+u]),
                         xin*bfu(wl[PW0+48+u]) + bfu(wl[PB0+48+u]),
                         xin*bfu(wl[PW0+80+u]) + bfu(wl[PB0+80+u]));
        float A0[32];
        #pragma unroll
        for (int k = 0; k < 16; k++) { A0[k] = __shfl(lo, gbase+k); A0[16+k] = __shfl(hi, gbase+k); }
        float gi = bfu(wl[PB1+u]), gg = bfu(wl[PB1+16+u]), go = bfu(wl[PB1+32+u]);
        int bi_ = (PW1 + u*36)>>2, bg_ = (PW1 + (16+u)*36)>>2, bo_ = (PW1 + (32+u)*36)>>2;
        #pragma unroll
        for (int q = 0; q < 8; q++) {
            uint2 wi = w2[bi_+q], wg = w2[bg_+q], wo = w2[bo_+q];
            float b0=A0[4*q], b1=A0[4*q+1], b2=A0[4*q+2], b3=A0[4*q+3];
            gi += b0*bflo(wi.x) + b1*bfhi(wi.x) + b2*bflo(wi.y) + b3*bfhi(wi.y);
            gg += b0*bflo(wg.x) + b1*bfhi(wg.x) + b2*bflo(wg.y) + b3*bfhi(wg.y);
            go += b0*bflo(wo.x) + b1*bfhi(wo.x) + b2*bflo(wo.y) + b3*bfhi(wo.y);
        }
        float a1 = dunit(gi, gg, go);
        float A1[16];
        #pragma unroll
        for (int k = 0; k < 16; k++) A1[k] = __shfl(a1, gbase+k);
        int v = u & 7;
        gi = bfu(wl[PB2+v]); gg = bfu(wl[PB2+8+v]); go = bfu(wl[PB2+16+v]);
        bi_ = (PW2 + v*20)>>2; bg_ = (PW2 + (8+v)*20)>>2; bo_ = (PW2 + (16+v)*20)>>2;
        #pragma unroll
        for (int q = 0; q < 4; q++) {
            uint2 wi = w2[bi_+q], wg = w2[bg_+q], wo = w2[bo_+q];
            float b0=A1[4*q], b1=A1[4*q+1], b2=A1[4*q+2], b3=A1[4*q+3];
            gi += b0*bflo(wi.x) + b1*bfhi(wi.x) + b2*bflo(wi.y) + b3*bfhi(wi.y);
            gg += b0*bflo(wg.x) + b1*bfhi(wg.x) + b2*bflo(wg.y) + b3*bfhi(wg.y);
            go += b0*bflo(wo.x) + b1*bfhi(wo.x) + b2*bflo(wo.y) + b3*bfhi(wo.y);
        }
        float a2 = dunit(gi, gg, go);
        float A2[8];
        #pragma unroll
        for (int k = 0; k < 8; k++) A2[k] = __shfl(a2, gbase+k);
        gi = bfu(wl[PB3+u]); gg = bfu(wl[PB3+16+u]); go = bfu(wl[PB3+32+u]);
        bi_ = (PW3 + u*12)>>2; bg_ = (PW3 + (16+u)*12)>>2; bo_ = (PW3 + (32+u)*12)>>2;
        #pragma unroll
        for (int q = 0; q < 2; q++) {
            uint2 wi = w2[bi_+q], wg = w2[bg_+q], wo = w2[bo_+q];
            float b0=A2[4*q], b1=A2[4*q+1], b2=A2[4*q+2], b3=A2[4*q+3];
            gi += b0*bflo(wi.x) + b1*bfhi(wi.x) + b2*bflo(wi.y) + b3*bfhi(wi.y);
            gg += b0*bflo(wg.x) + b1*bfhi(wg.x) + b2*bflo(wg.y) + b3*bfhi(wg.y);
            go += b0*bflo(wo.x) + b1*bfhi(wo.x) + b2*bflo(wo.y) + b3*bfhi(wo.y);
        }
        float a3 = dunit(gi, gg, go);
        float A3[16];
        #pragma unroll
        for (int k = 0; k < 16; k++) A3[k] = __shfl(a3, gbase+k);
        float part;
        {
            float g0i = bfu(wl[PB4+u]),    g0g = bfu(wl[PB4+32+u]), g0o = bfu(wl[PB4+64+u]);
            float g1i = bfu(wl[PB4+16+u]), g1g = bfu(wl[PB4+48+u]), g1o = bfu(wl[PB4+80+u]);
            int c0i = (PW4 + u*20)>>2,      c0g = (PW4 + (32+u)*20)>>2, c0o = (PW4 + (64+u)*20)>>2;
            int c1i = (PW4 + (16+u)*20)>>2, c1g = (PW4 + (48+u)*20)>>2, c1o = (PW4 + (80+u)*20)>>2;
            #pragma unroll
            for (int q = 0; q < 4; q++) {
                float b0=A3[4*q], b1=A3[4*q+1], b2=A3[4*q+2], b3=A3[4*q+3];
                uint2 wi = w2[c0i+q], wg = w2[c0g+q], wo = w2[c0o+q];
                g0i += b0*bflo(wi.x) + b1*bfhi(wi.x) + b2*bflo(wi.y) + b3*bfhi(wi.y);
                g0g += b0*bflo(wg.x) + b1*bfhi(wg.x) + b2*bflo(wg.y) + b3*bfhi(wg.y);
                g0o += b0*bflo(wo.x) + b1*bfhi(wo.x) + b2*bflo(wo.y) + b3*bfhi(wo.y);
                wi = w2[c1i+q]; wg = w2[c1g+q]; wo = w2[c1o+q];
                g1i += b0*bflo(wi.x) + b1*bfhi(wi.x) + b2*bflo(wi.y) + b3*bfhi(wi.y);
                g1g += b0*bflo(wg.x) + b1*bfhi(wg.x) + b2*bflo(wg.y) + b3*bfhi(wg.y);
                g1o += b0*bflo(wo.x) + b1*bfhi(wo.x) + b2*bflo(wo.y) + b3*bfhi(wo.y);
            }
            part = dunit(g0i, g0g, g0o)*bfu(wl[POW+u]) + dunit(g1i, g1g, g1o)*bfu(wl[POW+16+u]);
        }
        part += __shfl_xor(part, 1);
        part += __shfl_xor(part, 2);
        part += __shfl_xor(part, 4);
        part += __shfl_xor(part, 8);
        if (u == 0 && gid < NTAB) ws[TAB + gid] = part + bfu(wl[POB]);
        return;
    }

    // ---------------- decoder block (batch-invariant scan) ----------------
    {
        float* dh = smem;
        float* dc = smem + 16;
        const float* Wih = a.p[12];
        const float* Whh = a.p[13];
        const float* bb  = a.p[14];
        const float* oW  = a.p[15];
        const float* ob  = a.p[16];
        float wii[16], wff[16], wgg[16], woo[16];
        float vii[16], vff[16], vgg[16], voo[16];
        float bi_r=0, bf_r=0, bg_r=0, bo_r=0;
        if (tid < 16) {
            int uu = tid;
            #pragma unroll
            for (int k = 0; k < 16; k++) {
                wii[k]=Wih[uu*16+k];      vii[k]=Whh[uu*16+k];
                wff[k]=Wih[(16+uu)*16+k]; vff[k]=Whh[(16+uu)*16+k];
                wgg[k]=Wih[(32+uu)*16+k]; vgg[k]=Whh[(32+uu)*16+k];
                woo[k]=Wih[(48+uu)*16+k]; voo[k]=Whh[(48+uu)*16+k];
            }
            bi_r=bb[uu]; bf_r=bb[16+uu]; bg_r=bb[32+uu]; bo_r=bb[48+uu];
            float gi = bi_r, gg = bg_r, go = bo_r;
            #pragma unroll
            for (int k = 0; k < 16; k++) {
                gi += 128.f * wii[k];
                gg += 128.f * wgg[k];
                go += 128.f * woo[k];
            }
            float cd0 = sigm(gi) * tanh_f(gg);
            dc[tid] = cd0; dh[tid] = sigm(go) * tanh_f(cd0);
        }
        __syncthreads();
        for (int t = 0; t < 16; t++) {
            float rx[16], rh[16], cold = 0.f;
            if (tid < 16) {
                #pragma unroll
                for (int k = 0; k < 16; k++) { rx[k] = dc[k]; rh[k] = dh[k]; }
                cold = dc[tid];
            }
            __syncthreads();
            if (tid < 16) {
                float gi = bi_r, gf = bf_r, gg = bg_r, go = bo_r;
                #pragma unroll
                for (int k = 0; k < 16; k++) {
                    gi += rx[k]*wii[k] + rh[k]*vii[k];
                    gf += rx[k]*wff[k] + rh[k]*vff[k];
                    gg += rx[k]*wgg[k] + rh[k]*vgg[k];
                    go += rx[k]*woo[k] + rh[k]*voo[k];
                }
                float cn = sigm(gf)*cold + sigm(gi)*tanh_f(gg);
                dc[tid] = cn; dh[tid] = sigm(go)*tanh_f(cn);
            }
            __syncthreads();
            if (tid == 0) {
                float o = ob[0];
                #pragma unroll
                for (int k = 0; k < 16; k++) o += dh[k] * oW[k];
                ws[RECO + t] = o;
            }
            __syncthreads();
        }
    }
}

// ---- k_post: 4 elements per thread; fcW/rec/table staged in LDS ----
__global__ __launch_bounds__(256) void k_post(P29 a, const int* __restrict__ masks,
                                              const float* __restrict__ ws,
                                              float* __restrict__ out)
{
    __shared__ float tab[NTAB];
    __shared__ __align__(16) float fw[256];
    __shared__ __align__(16) float rec[16];
    __shared__ float fb[16];
    int tid = threadIdx.x;
    for (int i = tid; i < NTAB; i += 256) tab[i] = ws[TAB + i];
    fw[tid] = a.p[10][tid];
    if (tid < 16) { fb[tid] = a.p[11][tid]; rec[tid] = ws[RECO + tid]; }
    __syncthreads();
    int T = blockIdx.x * 256 + tid;
    int b = T >> 2;
    int q = T & 3;
    int tq = q * 4;
    const float4* hf4 = (const float4*)(ws + HFO + (size_t)b*16);
    const float4* hb4 = (const float4*)(ws + HBO + (size_t)b*16);
    float4 s0, s1, s2, s3;
    {
        float4 f0=hf4[0], f1=hf4[1], f2=hf4[2], f3=hf4[3];
        float4 g0=hb4[0], g1=hb4[1], g2=hb4[2], g3=hb4[3];
        s0 = make_float4(f0.x+g0.x, f0.y+g0.y, f0.z+g0.z, f0.w+g0.w);
        s1 = make_float4(f1.x+g1.x, f1.y+g1.y, f1.z+g1.z, f1.w+g1.w);
        s2 = make_float4(f2.x+g2.x, f2.y+g2.y, f2.z+g2.z, f2.w+g2.w);
        s3 = make_float4(f3.x+g3.x, f3.y+g3.y, f3.z+g3.z, f3.w+g3.w);
    }
    float4 hq = (q==0) ? s0 : (q==1) ? s1 : (q==2) ? s2 : s3;
    float4 xv = *(const float4*)(a.p[0] + (size_t)b*16 + tq);
    int4   mv = *(const int4*)(masks + (size_t)b*16 + tq);
    float impv[4];
    impv[0] = mv.x ? xv.x : hq.x;
    impv[1] = mv.y ? xv.y : hq.y;
    impv[2] = mv.z ? xv.z : hq.z;
    impv[3] = mv.w ? xv.w : hq.w;
    float latv[4];
    #pragma unroll
    for (int j = 0; j < 4; j++) {
        int t = tq + j;
        const float4* wr = (const float4*)(fw + t*16);
        float4 w0=wr[0], w1=wr[1], w2=wr[2], w3=wr[3];
        float l = fb[t];
        l += s0.x*w0.x + s0.y*w0.y + s0.z*w0.z + s0.w*w0.w;
        l += s1.x*w1.x + s1.y*w1.y + s1.z*w1.z + s1.w*w1.w;
        l += s2.x*w2.x + s2.y*w2.y + s2.z*w2.z + s2.w*w2.w;
        l += s3.x*w3.x + s3.y*w3.y + s3.z*w3.z + s3.w*w3.w;
        latv[j] = l;
    }
    float dv[4];
    #pragma unroll
    for (int j = 0; j < 4; j++) {
        float xx = fminf(fmaxf(impv[j], -8.f), 8.f);
        float f = (xx + 8.f) * 128.f;
        float fi = floorf(f);
        int i = (int)fi; i = i > NTAB-2 ? NTAB-2 : i;
        float w = f - fi;
        dv[j] = fmaf(w, tab[i+1] - tab[i], tab[i]);
    }
    float4 rv = ((const float4*)rec)[q];
    size_t eo = (size_t)b*16 + tq;
    *(float4*)(out + eo)        = make_float4(impv[0], impv[1], impv[2], impv[3]);
    *(float4*)(out + BS + eo)   = make_float4(dv[0], dv[1], dv[2], dv[3]);
    *(float4*)(out + 2*BS + eo) = make_float4(latv[0], latv[1], latv[2], latv[3]);
    *(float4*)(out + 3*BS + eo) = rv;
}

extern "C" void kernel_launch(void* const* d_in, const int* in_sizes, int n_in,
                              void* d_out, int out_size, void* d_ws, size_t ws_size,
                              hipStream_t stream)
{
    float* ws = (float*)d_ws;
    P29 a;
    for (int i = 0; i < 29; i++) a.p[i] = (const float*)d_in[i];
    const int* masks = (const int*)d_in[1];
    k_main<<<NSCAN + NTABB + 1, 256, 0, stream>>>(a, masks, ws);  // scan ∥ table ∥ decoder
    k_post<<<(BB*4)/256, 256, 0, stream>>>(a, masks, ws, (float*)d_out);
}